// Round 7
// baseline (243.049 us; speedup 1.0000x reference)
//
#include <hip/hip_runtime.h>

#define EPS_BN 1e-5f

// Problem constants: B=8, CH=64, H=W=64  (all I/O float32)
constexpr int Bn   = 8;
constexpr int CHn  = 64;
constexpr int HWn  = 4096;   // 64*64
constexpr int HW4n = 1024;   // pooled
constexpr int CQn  = 8;      // CH/8
constexpr int CVn  = 32;     // CH/2

// Module-scope scratch; fully rewritten every call.
// g_K: [b][m][8]                 (256 KiB)
// g_V: [b][q4(8)][row(1024)][4]  (1 MiB)  -- channel-group-major
__device__ __align__(16) float g_K[Bn * HW4n * CQn];
__device__ __align__(16) float g_V[Bn * HW4n * CVn];

// ------------- Kernel A: K,V projection + BN + 2x2 maxpool -------------------
// 256 blocks x 192 threads. Block = one pooled row (32 pooled px) of one batch.
__global__ __launch_bounds__(192)
void k_proj_kv(const float* __restrict__ mem,
               const float* __restrict__ wk,  const float* __restrict__ bk,
               const float* __restrict__ ks,  const float* __restrict__ kb,
               const float* __restrict__ km,  const float* __restrict__ kv,
               const float* __restrict__ wv,  const float* __restrict__ bv_,
               const float* __restrict__ vs,  const float* __restrict__ vb,
               const float* __restrict__ vm,  const float* __restrict__ vv)
{
    __shared__ float wall[2560];   // [ch][40]: c 0..7 = K, 8..39 = V (BN folded)
    __shared__ float beta[40];
    __shared__ float Msh[8192];    // [ch][32 quads][4 px], 32 KB

    const int tid = threadIdx.x;
    for (int idx = tid; idx < 2560; idx += 192) {
        int c = idx % 40, ch = idx / 40;
        float w, inv;
        if (c < 8) { inv = ks[c] * rsqrtf(kv[c] + EPS_BN); w = wk[c * 64 + ch]; }
        else { int c2 = c - 8; inv = vs[c2] * rsqrtf(vv[c2] + EPS_BN); w = wv[c2 * 64 + ch]; }
        wall[ch * 40 + c] = w * inv;
    }
    if (tid < 40) {
        int c = tid;
        if (c < 8) {
            float inv = ks[c] * rsqrtf(kv[c] + EPS_BN);
            beta[c] = (bk[c] - km[c]) * inv + kb[c];
        } else {
            int c2 = c - 8;
            float inv = vs[c2] * rsqrtf(vv[c2] + EPS_BN);
            beta[c] = (bv_[c2] - vm[c2]) * inv + vb[c2];
        }
    }

    const int b = blockIdx.x >> 5;        // 32 blocks per batch
    const int R = blockIdx.x & 31;        // pooled row

    // ---- stage source tile: rows 2R,2R+1, all 64 cols, all 64 ch ----
    {
        const float* src = mem + (size_t)b * (CHn * HWn) + (R << 7);
        for (int idx = tid; idx < 4096; idx += 192) {
            int ch = idx >> 6, p2 = idx & 63;
            float2 v = *(const float2*)(src + ch * HWn + (p2 << 1));
            int r = p2 >> 5, w2 = p2 & 31;
            *(float2*)&Msh[ch * 128 + (w2 << 2) + (r << 1)] = v;
        }
    }
    __syncthreads();

    if (tid < 160) {
        const int g  = tid % 5;        // out group: 0 = K(8ch), 1..4 = V 8ch each
        const int qd = tid / 5;        // pooled col 0..31
        float acc[4][8];
        #pragma unroll
        for (int p = 0; p < 4; ++p)
            #pragma unroll
            for (int c = 0; c < 8; ++c) acc[p][c] = 0.f;

        for (int ch = 0; ch < 64; ++ch) {
            const float4 mq = *(const float4*)&Msh[ch * 128 + (qd << 2)];
            const float4* wr = (const float4*)&wall[ch * 40 + (g << 3)];
            const float4 w0 = wr[0], w1 = wr[1];
            #pragma unroll
            for (int p = 0; p < 4; ++p) {
                const float mv = (p == 0) ? mq.x : (p == 1) ? mq.y : (p == 2) ? mq.z : mq.w;
                acc[p][0] = fmaf(w0.x, mv, acc[p][0]); acc[p][1] = fmaf(w0.y, mv, acc[p][1]);
                acc[p][2] = fmaf(w0.z, mv, acc[p][2]); acc[p][3] = fmaf(w0.w, mv, acc[p][3]);
                acc[p][4] = fmaf(w1.x, mv, acc[p][4]); acc[p][5] = fmaf(w1.y, mv, acc[p][5]);
                acc[p][6] = fmaf(w1.z, mv, acc[p][6]); acc[p][7] = fmaf(w1.w, mv, acc[p][7]);
            }
        }
        float o[8];
        #pragma unroll
        for (int c = 0; c < 8; ++c)
            o[c] = fmaxf(fmaxf(acc[0][c], acc[1][c]), fmaxf(acc[2][c], acc[3][c]))
                 + beta[(g << 3) + c];

        const int m = (R << 5) + qd;
        if (g == 0) {
            float4* kp = (float4*)(g_K + ((size_t)b * HW4n + m) * CQn);
            kp[0] = make_float4(o[0], o[1], o[2], o[3]);
            kp[1] = make_float4(o[4], o[5], o[6], o[7]);
        } else {
            float4* vp = (float4*)(g_V + (size_t)b * (HW4n * CVn)
                                       + (size_t)((g - 1) << 1) * (HW4n * 4)) + m;
            vp[0]     = make_float4(o[0], o[1], o[2], o[3]);
            vp[1024]  = make_float4(o[4], o[5], o[6], o[7]);
        }
    }
}

// ------ Kernel B: fused Q-proj + online-softmax attention + out-proj ---------
// 512 blocks x 256 threads, pinned 2 waves/EU (VGPR cap 256, no spill-for-occ).
// 16-lane group owns 4 queries; lane (h=bit3, j=bits0..2): keys ≡ j (mod 8),
// V/acc channels [16h, 16h+16). K in LDS (staged once, no mid-loop barriers);
// V read directly from global (L1/L2-resident, [q4][row] line-friendly).
__global__ __launch_bounds__(256, 2) __attribute__((amdgpu_waves_per_eu(2, 2)))
void k_attn4(const float* __restrict__ mem,
             const float* __restrict__ x,
             const float* __restrict__ wq, const float* __restrict__ bq,
             const float* __restrict__ qs, const float* __restrict__ qb,
             const float* __restrict__ qm, const float* __restrict__ qv,
             const float* __restrict__ wp, const float* __restrict__ bp,
             const float* __restrict__ ps, const float* __restrict__ pb,
             const float* __restrict__ pm, const float* __restrict__ pv,
             const float* __restrict__ gamma,
             float* __restrict__ out)
{
    __shared__ float qw[512];      // folded Q weights [ch][8]
    __shared__ float qbeta[8];
    __shared__ float wpf[2048];    // folded out-proj weights [o][32]
    __shared__ float pbeta[64];
    __shared__ float Ksh[8192];    // K[1024][8], 32 KB
    __shared__ float Gsh[2308];    // g exchange: [64 q][36] (32 ch + l at 32)

    const int tid  = threadIdx.x;
    const int j    = tid & 7;            // key-split lane
    const int h    = (tid >> 3) & 1;     // channel half
    const int j16  = tid & 15;
    const int grp  = tid >> 4;           // 0..15, 4 queries each
    const int b    = blockIdx.x >> 6;    // 64 tiles per batch
    const int tile = blockIdx.x & 63;
    const int n0   = (tile << 6) + (grp << 2);   // group's first query

    // ---- stage folded weights ----
    const float gm = gamma[0];
    for (int idx = tid; idx < 512; idx += 256) {
        int c = idx & 7, ch = idx >> 3;
        float inv = qs[c] * rsqrtf(qv[c] + EPS_BN);
        qw[idx] = wq[c * 64 + ch] * inv;
    }
    if (tid < 8) {
        float inv = qs[tid] * rsqrtf(qv[tid] + EPS_BN);
        qbeta[tid] = (bq[tid] - qm[tid]) * inv + qb[tid];
    }
    for (int idx = tid; idx < 2048; idx += 256) {
        int o = idx >> 5, cc = idx & 31;
        float inv = ps[o] * rsqrtf(pv[o] + EPS_BN);
        wpf[idx] = wp[o * 32 + cc] * inv * gm;
    }
    if (tid < 64) {
        float inv = ps[tid] * rsqrtf(pv[tid] + EPS_BN);
        pbeta[tid] = gm * ((bp[tid] - pm[tid]) * inv + pb[tid]);
    }
    // ---- stage K (this batch) ----
    {
        const float4* Ks4 = (const float4*)(g_K + (size_t)b * (HW4n * CQn));
        float4* Kd4 = (float4*)Ksh;
        #pragma unroll
        for (int i = 0; i < 8; ++i) Kd4[(i << 8) | tid] = Ks4[(i << 8) | tid];
    }
    __syncthreads();

    // ---- Q projection: lane j16 handles ch ≡ j16 (mod 16), 4 queries ----
    float qreg[4][8];
    #pragma unroll
    for (int qq = 0; qq < 4; ++qq)
        #pragma unroll
        for (int c = 0; c < 8; ++c) qreg[qq][c] = 0.f;
    {
        const float* mp = mem + (size_t)b * (CHn * HWn) + n0;
        #pragma unroll
        for (int cc = 0; cc < 4; ++cc) {
            int ch = (cc << 4) | j16;
            float4 mv4 = *(const float4*)(mp + ch * HWn);   // 4 queries
            const float4* wr = (const float4*)&qw[ch * 8];
            float4 w0 = wr[0], w1 = wr[1];
            #pragma unroll
            for (int qq = 0; qq < 4; ++qq) {
                const float mv = (qq == 0) ? mv4.x : (qq == 1) ? mv4.y : (qq == 2) ? mv4.z : mv4.w;
                qreg[qq][0] = fmaf(w0.x, mv, qreg[qq][0]); qreg[qq][1] = fmaf(w0.y, mv, qreg[qq][1]);
                qreg[qq][2] = fmaf(w0.z, mv, qreg[qq][2]); qreg[qq][3] = fmaf(w0.w, mv, qreg[qq][3]);
                qreg[qq][4] = fmaf(w1.x, mv, qreg[qq][4]); qreg[qq][5] = fmaf(w1.y, mv, qreg[qq][5]);
                qreg[qq][6] = fmaf(w1.z, mv, qreg[qq][6]); qreg[qq][7] = fmaf(w1.w, mv, qreg[qq][7]);
            }
        }
        #pragma unroll
        for (int qq = 0; qq < 4; ++qq)
            #pragma unroll
            for (int c = 0; c < 8; ++c) {
                float v = qreg[qq][c];
                v += __shfl_xor(v, 1); v += __shfl_xor(v, 2);
                v += __shfl_xor(v, 4); v += __shfl_xor(v, 8);
                qreg[qq][c] = v + qbeta[c];
            }
    }

    const float4* K4 = (const float4*)Ksh;
    const float4* Vg = (const float4*)(g_V + (size_t)b * (HW4n * CVn)) + (h << 12);

    // ---- online softmax state (channels [16h, 16h+16)) ----
    float m_[4], l_[4], acc[4][16];
    #pragma unroll
    for (int qq = 0; qq < 4; ++qq) {
        m_[qq] = -3.0e38f; l_[qq] = 0.f;
        #pragma unroll
        for (int c = 0; c < 16; ++c) acc[qq][c] = 0.f;
    }

    for (int blk = 0; blk < 16; ++blk) {
        // ---- scores: 8 keys/lane, 4 queries ----
        float s[4][8];
        #pragma unroll
        for (int mm = 0; mm < 8; ++mm) {
            const int m = (blk << 6) | (mm << 3) | j;
            const float4 k0 = K4[2 * m], k1 = K4[2 * m + 1];
            #pragma unroll
            for (int qq = 0; qq < 4; ++qq) {
                const float* q = qreg[qq];
                s[qq][mm] = fmaf(q[0], k0.x, fmaf(q[1], k0.y, fmaf(q[2], k0.z, fmaf(q[3], k0.w,
                            fmaf(q[4], k1.x, fmaf(q[5], k1.y, fmaf(q[6], k1.z, q[7] * k1.w)))))));
            }
        }
        // ---- online update + exp ----
        #pragma unroll
        for (int qq = 0; qq < 4; ++qq) {
            float cm = s[qq][0];
            #pragma unroll
            for (int mm = 1; mm < 8; ++mm) cm = fmaxf(cm, s[qq][mm]);
            float mn = fmaxf(m_[qq], cm);
            float al = __expf(m_[qq] - mn);
            m_[qq] = mn;
            l_[qq] *= al;
            #pragma unroll
            for (int cc = 0; cc < 16; ++cc) acc[qq][cc] *= al;
            #pragma unroll
            for (int mm = 0; mm < 8; ++mm) {
                float e = __expf(s[qq][mm] - mn);
                s[qq][mm] = e;
                l_[qq] += e;
            }
        }
        // ---- PV: V from global (L1/L2), lane's 16 channels, 4 queries ----
        #pragma unroll
        for (int mm = 0; mm < 8; ++mm) {
            const int m = (blk << 6) | (mm << 3) | j;
            #pragma unroll
            for (int i = 0; i < 4; ++i) {
                const float4 vv = Vg[(i << 10) + m];
                #pragma unroll
                for (int qq = 0; qq < 4; ++qq) {
                    const float e = s[qq][mm];
                    acc[qq][4*i+0] = fmaf(e, vv.x, acc[qq][4*i+0]);
                    acc[qq][4*i+1] = fmaf(e, vv.y, acc[qq][4*i+1]);
                    acc[qq][4*i+2] = fmaf(e, vv.z, acc[qq][4*i+2]);
                    acc[qq][4*i+3] = fmaf(e, vv.w, acc[qq][4*i+3]);
                }
            }
        }
    }

    // ---- merge across j (xor 1,2,4; both h-halves redundant in m/l) ----
    #pragma unroll
    for (int qq = 0; qq < 4; ++qq) {
        float M = m_[qq];
        M = fmaxf(M, __shfl_xor(M, 1)); M = fmaxf(M, __shfl_xor(M, 2)); M = fmaxf(M, __shfl_xor(M, 4));
        float a = __expf(m_[qq] - M);
        float lv = l_[qq] * a;
        lv += __shfl_xor(lv, 1); lv += __shfl_xor(lv, 2); lv += __shfl_xor(lv, 4);
        l_[qq] = lv;
        #pragma unroll
        for (int cc = 0; cc < 16; ++cc) {
            float v = acc[qq][cc] * a;
            v += __shfl_xor(v, 1); v += __shfl_xor(v, 2); v += __shfl_xor(v, 4);
            acc[qq][cc] = v;
        }
    }

    // ---- exchange via LDS: lane j writes query (j&3), 8-ch piece (j>>2) ----
    {
        const int qq = j & 3, p = j >> 2;
        float* dst = &Gsh[(grp * 4 + qq) * 36 + h * 16 + p * 8];
        ((float4*)dst)[0] = make_float4(acc[qq][p*8+0], acc[qq][p*8+1], acc[qq][p*8+2], acc[qq][p*8+3]);
        ((float4*)dst)[1] = make_float4(acc[qq][p*8+4], acc[qq][p*8+5], acc[qq][p*8+6], acc[qq][p*8+7]);
        if (h == 0 && j < 4) Gsh[(grp * 4 + j) * 36 + 32] = l_[j];
    }
    __syncthreads();

    // ---- epilogue: thread t -> query t>>2, channel-quarter t&3 ----
    {
        const int q = tid >> 2, r = tid & 3;
        const float rL = 1.0f / Gsh[q * 36 + 32];
        const float4* gq4 = (const float4*)&Gsh[q * 36 + r * 8];
        const float4 gA = gq4[0], gB = gq4[1];
        const float4 g0 = make_float4(gA.x * rL, gA.y * rL, gA.z * rL, gA.w * rL);
        const float4 g1 = make_float4(gB.x * rL, gB.y * rL, gB.z * rL, gB.w * rL);

        const int n = (tile << 6) + q;
        const float* xp = x + (size_t)b * (CHn * HWn) + n;
        float* op = out + (size_t)b * (CHn * HWn) + n;
        const float4* wpf4 = (const float4*)wpf;

        float red[64];
        for (int o = 0; o < 64; ++o) {
            const float4 wA = wpf4[o * 8 + 2 * r];
            const float4 wB = wpf4[o * 8 + 2 * r + 1];
            float po = wA.x * g0.x + wA.y * g0.y + wA.z * g0.z + wA.w * g0.w
                     + wB.x * g1.x + wB.y * g1.y + wB.z * g1.z + wB.w * g1.w;
            po += __shfl_xor(po, 1);
            po += __shfl_xor(po, 2);
            red[o] = po;
        }
        #pragma unroll 4
        for (int oo = 0; oo < 16; ++oo) {
            const int o = (r << 4) | oo;
            op[o * HWn] = xp[o * HWn] + pbeta[o] + red[o];
        }
    }
}

// ------------------------------- launcher ------------------------------------
extern "C" void kernel_launch(void* const* d_in, const int* in_sizes, int n_in,
                              void* d_out, int out_size, void* d_ws, size_t ws_size,
                              hipStream_t stream)
{
    const float* x    = (const float*)d_in[0];
    const float* mem  = (const float*)d_in[1];
    const float* wq   = (const float*)d_in[2];
    const float* bq   = (const float*)d_in[3];
    const float* bnqs = (const float*)d_in[4];
    const float* bnqb = (const float*)d_in[5];
    const float* bnqm = (const float*)d_in[6];
    const float* bnqv = (const float*)d_in[7];
    const float* wk   = (const float*)d_in[8];
    const float* bk   = (const float*)d_in[9];
    const float* bnks = (const float*)d_in[10];
    const float* bnkb = (const float*)d_in[11];
    const float* bnkm = (const float*)d_in[12];
    const float* bnkv = (const float*)d_in[13];
    const float* wv   = (const float*)d_in[14];
    const float* bv   = (const float*)d_in[15];
    const float* bnvs = (const float*)d_in[16];
    const float* bnvb = (const float*)d_in[17];
    const float* bnvm = (const float*)d_in[18];
    const float* bnvv = (const float*)d_in[19];
    const float* wp   = (const float*)d_in[20];
    const float* bp   = (const float*)d_in[21];
    const float* bnps = (const float*)d_in[22];
    const float* bnpb = (const float*)d_in[23];
    const float* bnpm = (const float*)d_in[24];
    const float* bnpv = (const float*)d_in[25];
    const float* gam  = (const float*)d_in[26];

    (void)d_ws; (void)ws_size; (void)in_sizes; (void)n_in; (void)out_size;

    k_proj_kv<<<dim3(256), dim3(192), 0, stream>>>(mem,
        wk, bk, bnks, bnkb, bnkm, bnkv,
        wv, bv, bnvs, bnvb, bnvm, bnvv);
    k_attn4<<<dim3(512), dim3(256), 0, stream>>>(mem, x,
        wq, bq, bnqs, bnqb, bnqm, bnqv,
        wp, bp, bnps, bnpb, bnpm, bnpv, gam,
        (float*)d_out);
}

// Round 8
// 228.920 us; speedup vs baseline: 1.0617x; 1.0617x over previous
//
#include <hip/hip_runtime.h>

#define EPS_BN 1e-5f

// Problem constants: B=8, CH=64, H=W=64  (all I/O float32)
constexpr int Bn   = 8;
constexpr int CHn  = 64;
constexpr int HWn  = 4096;   // 64*64
constexpr int HW4n = 1024;   // pooled
constexpr int CQn  = 8;      // CH/8
constexpr int CVn  = 32;     // CH/2

// Module-scope scratch; fully rewritten every call.
// g_K: [b][m][8]                 (256 KiB)
// g_V: [b][q4(8)][row(1024)][4]  (1 MiB)  -- channel-group-major
__device__ __align__(16) float g_K[Bn * HW4n * CQn];
__device__ __align__(16) float g_V[Bn * HW4n * CVn];

// ------------- Kernel A: K,V projection + BN + 2x2 maxpool -------------------
// 256 blocks x 192 threads. Block = one pooled row (32 pooled px) of one batch.
__global__ __launch_bounds__(192)
void k_proj_kv(const float* __restrict__ mem,
               const float* __restrict__ wk,  const float* __restrict__ bk,
               const float* __restrict__ ks,  const float* __restrict__ kb,
               const float* __restrict__ km,  const float* __restrict__ kv,
               const float* __restrict__ wv,  const float* __restrict__ bv_,
               const float* __restrict__ vs,  const float* __restrict__ vb,
               const float* __restrict__ vm,  const float* __restrict__ vv)
{
    __shared__ float wall[2560];   // [ch][40]: c 0..7 = K, 8..39 = V (BN folded)
    __shared__ float beta[40];
    __shared__ float Msh[8192];    // [ch][32 quads][4 px], 32 KB

    const int tid = threadIdx.x;
    for (int idx = tid; idx < 2560; idx += 192) {
        int c = idx % 40, ch = idx / 40;
        float w, inv;
        if (c < 8) { inv = ks[c] * rsqrtf(kv[c] + EPS_BN); w = wk[c * 64 + ch]; }
        else { int c2 = c - 8; inv = vs[c2] * rsqrtf(vv[c2] + EPS_BN); w = wv[c2 * 64 + ch]; }
        wall[ch * 40 + c] = w * inv;
    }
    if (tid < 40) {
        int c = tid;
        if (c < 8) {
            float inv = ks[c] * rsqrtf(kv[c] + EPS_BN);
            beta[c] = (bk[c] - km[c]) * inv + kb[c];
        } else {
            int c2 = c - 8;
            float inv = vs[c2] * rsqrtf(vv[c2] + EPS_BN);
            beta[c] = (bv_[c2] - vm[c2]) * inv + vb[c2];
        }
    }

    const int b = blockIdx.x >> 5;        // 32 blocks per batch
    const int R = blockIdx.x & 31;        // pooled row

    // ---- stage source tile: rows 2R,2R+1, all 64 cols, all 64 ch ----
    {
        const float* src = mem + (size_t)b * (CHn * HWn) + (R << 7);
        for (int idx = tid; idx < 4096; idx += 192) {
            int ch = idx >> 6, p2 = idx & 63;
            float2 v = *(const float2*)(src + ch * HWn + (p2 << 1));
            int r = p2 >> 5, w2 = p2 & 31;
            *(float2*)&Msh[ch * 128 + (w2 << 2) + (r << 1)] = v;
        }
    }
    __syncthreads();

    if (tid < 160) {
        const int g  = tid % 5;        // out group: 0 = K(8ch), 1..4 = V 8ch each
        const int qd = tid / 5;        // pooled col 0..31
        float acc[4][8];
        #pragma unroll
        for (int p = 0; p < 4; ++p)
            #pragma unroll
            for (int c = 0; c < 8; ++c) acc[p][c] = 0.f;

        for (int ch = 0; ch < 64; ++ch) {
            const float4 mq = *(const float4*)&Msh[ch * 128 + (qd << 2)];
            const float4* wr = (const float4*)&wall[ch * 40 + (g << 3)];
            const float4 w0 = wr[0], w1 = wr[1];
            #pragma unroll
            for (int p = 0; p < 4; ++p) {
                const float mv = (p == 0) ? mq.x : (p == 1) ? mq.y : (p == 2) ? mq.z : mq.w;
                acc[p][0] = fmaf(w0.x, mv, acc[p][0]); acc[p][1] = fmaf(w0.y, mv, acc[p][1]);
                acc[p][2] = fmaf(w0.z, mv, acc[p][2]); acc[p][3] = fmaf(w0.w, mv, acc[p][3]);
                acc[p][4] = fmaf(w1.x, mv, acc[p][4]); acc[p][5] = fmaf(w1.y, mv, acc[p][5]);
                acc[p][6] = fmaf(w1.z, mv, acc[p][6]); acc[p][7] = fmaf(w1.w, mv, acc[p][7]);
            }
        }
        float o[8];
        #pragma unroll
        for (int c = 0; c < 8; ++c)
            o[c] = fmaxf(fmaxf(acc[0][c], acc[1][c]), fmaxf(acc[2][c], acc[3][c]))
                 + beta[(g << 3) + c];

        const int m = (R << 5) + qd;
        if (g == 0) {
            float4* kp = (float4*)(g_K + ((size_t)b * HW4n + m) * CQn);
            kp[0] = make_float4(o[0], o[1], o[2], o[3]);
            kp[1] = make_float4(o[4], o[5], o[6], o[7]);
        } else {
            float4* vp = (float4*)(g_V + (size_t)b * (HW4n * CVn)
                                       + (size_t)((g - 1) << 1) * (HW4n * 4)) + m;
            vp[0]     = make_float4(o[0], o[1], o[2], o[3]);
            vp[1024]  = make_float4(o[4], o[5], o[6], o[7]);
        }
    }
}

// ------ Kernel B: fused Q-proj + online-softmax attention + out-proj ---------
// 512 blocks x 256 threads, 2 waves/EU pinned. 16-lane group owns 4 queries;
// lane (h=bit3, j=bits0..2): keys ≡ j (mod 8), V/acc channels [16h,16h+16).
// K in LDS (staged once, NO mid-loop barriers); V direct from global (L2).
// No dynamically-indexed private arrays anywhere (spill-free by construction).
__global__ __launch_bounds__(256, 2) __attribute__((amdgpu_waves_per_eu(2, 2)))
void k_attn5(const float* __restrict__ mem,
             const float* __restrict__ x,
             const float* __restrict__ wq, const float* __restrict__ bq,
             const float* __restrict__ qs, const float* __restrict__ qb,
             const float* __restrict__ qm, const float* __restrict__ qv,
             const float* __restrict__ wp, const float* __restrict__ bp,
             const float* __restrict__ ps, const float* __restrict__ pb,
             const float* __restrict__ pm, const float* __restrict__ pv,
             const float* __restrict__ gamma,
             float* __restrict__ out)
{
    __shared__ float qw[512];      // folded Q weights [ch][8]
    __shared__ float qbeta[8];
    __shared__ float wpf[2304];    // folded out-proj weights [o][36-pitch]
    __shared__ float pbeta[64];
    __shared__ float Ksh[8192];    // K[1024][8], 32 KB
    __shared__ float Gsh[2304];    // g exchange: [64 q][36] (32 ch + l at 32)

    const int tid  = threadIdx.x;
    const int j    = tid & 7;            // key-split lane
    const int h    = (tid >> 3) & 1;     // channel half
    const int j16  = tid & 15;
    const int grp  = tid >> 4;           // 0..15, 4 queries each
    const int b    = blockIdx.x >> 6;    // 64 tiles per batch
    const int tile = blockIdx.x & 63;
    const int n0   = (tile << 6) + (grp << 2);   // group's first query

    // ---- stage folded weights ----
    const float gm = gamma[0];
    for (int idx = tid; idx < 512; idx += 256) {
        int c = idx & 7, ch = idx >> 3;
        float inv = qs[c] * rsqrtf(qv[c] + EPS_BN);
        qw[idx] = wq[c * 64 + ch] * inv;
    }
    if (tid < 8) {
        float inv = qs[tid] * rsqrtf(qv[tid] + EPS_BN);
        qbeta[tid] = (bq[tid] - qm[tid]) * inv + qb[tid];
    }
    for (int idx = tid; idx < 2048; idx += 256) {
        int o = idx >> 5, cc = idx & 31;
        float inv = ps[o] * rsqrtf(pv[o] + EPS_BN);
        wpf[o * 36 + cc] = wp[o * 32 + cc] * inv * gm;   // pitch 36: bank-spread
    }
    if (tid < 64) {
        float inv = ps[tid] * rsqrtf(pv[tid] + EPS_BN);
        pbeta[tid] = gm * ((bp[tid] - pm[tid]) * inv + pb[tid]);
    }
    // ---- stage K (this batch) ----
    {
        const float4* Ks4 = (const float4*)(g_K + (size_t)b * (HW4n * CQn));
        float4* Kd4 = (float4*)Ksh;
        #pragma unroll
        for (int i = 0; i < 8; ++i) Kd4[(i << 8) | tid] = Ks4[(i << 8) | tid];
    }
    __syncthreads();

    // ---- Q projection: lane j16 handles ch ≡ j16 (mod 16), 4 queries ----
    float qreg[4][8];
    #pragma unroll
    for (int qq = 0; qq < 4; ++qq)
        #pragma unroll
        for (int c = 0; c < 8; ++c) qreg[qq][c] = 0.f;
    {
        const float* mp = mem + (size_t)b * (CHn * HWn) + n0;
        #pragma unroll
        for (int cc = 0; cc < 4; ++cc) {
            int ch = (cc << 4) | j16;
            float4 mv4 = *(const float4*)(mp + ch * HWn);   // 4 queries
            const float4* wr = (const float4*)&qw[ch * 8];
            float4 w0 = wr[0], w1 = wr[1];
            #pragma unroll
            for (int qq = 0; qq < 4; ++qq) {
                const float mv = (qq == 0) ? mv4.x : (qq == 1) ? mv4.y : (qq == 2) ? mv4.z : mv4.w;
                qreg[qq][0] = fmaf(w0.x, mv, qreg[qq][0]); qreg[qq][1] = fmaf(w0.y, mv, qreg[qq][1]);
                qreg[qq][2] = fmaf(w0.z, mv, qreg[qq][2]); qreg[qq][3] = fmaf(w0.w, mv, qreg[qq][3]);
                qreg[qq][4] = fmaf(w1.x, mv, qreg[qq][4]); qreg[qq][5] = fmaf(w1.y, mv, qreg[qq][5]);
                qreg[qq][6] = fmaf(w1.z, mv, qreg[qq][6]); qreg[qq][7] = fmaf(w1.w, mv, qreg[qq][7]);
            }
        }
        #pragma unroll
        for (int qq = 0; qq < 4; ++qq)
            #pragma unroll
            for (int c = 0; c < 8; ++c) {
                float v = qreg[qq][c];
                v += __shfl_xor(v, 1); v += __shfl_xor(v, 2);
                v += __shfl_xor(v, 4); v += __shfl_xor(v, 8);
                qreg[qq][c] = v + qbeta[c];
            }
    }

    const float4* K4 = (const float4*)Ksh;
    const float4* Vg = (const float4*)(g_V + (size_t)b * (HW4n * CVn)) + (h << 12);

    // ---- online softmax state (channels [16h, 16h+16)) ----
    float m_[4], l_[4], acc[4][16];
    #pragma unroll
    for (int qq = 0; qq < 4; ++qq) {
        m_[qq] = -3.0e38f; l_[qq] = 0.f;
        #pragma unroll
        for (int c = 0; c < 16; ++c) acc[qq][c] = 0.f;
    }

    for (int blk = 0; blk < 16; ++blk) {
        // ---- scores: 8 keys/lane, 4 queries ----
        float s[4][8];
        #pragma unroll
        for (int mm = 0; mm < 8; ++mm) {
            const int m = (blk << 6) | (mm << 3) | j;
            const float4 k0 = K4[2 * m], k1 = K4[2 * m + 1];
            #pragma unroll
            for (int qq = 0; qq < 4; ++qq) {
                const float* q = qreg[qq];
                s[qq][mm] = fmaf(q[0], k0.x, fmaf(q[1], k0.y, fmaf(q[2], k0.z, fmaf(q[3], k0.w,
                            fmaf(q[4], k1.x, fmaf(q[5], k1.y, fmaf(q[6], k1.z, q[7] * k1.w)))))));
            }
        }
        // ---- online update + exp ----
        #pragma unroll
        for (int qq = 0; qq < 4; ++qq) {
            float cm = s[qq][0];
            #pragma unroll
            for (int mm = 1; mm < 8; ++mm) cm = fmaxf(cm, s[qq][mm]);
            float mn = fmaxf(m_[qq], cm);
            float al = __expf(m_[qq] - mn);
            m_[qq] = mn;
            l_[qq] *= al;
            #pragma unroll
            for (int cc = 0; cc < 16; ++cc) acc[qq][cc] *= al;
            #pragma unroll
            for (int mm = 0; mm < 8; ++mm) {
                float e = __expf(s[qq][mm] - mn);
                s[qq][mm] = e;
                l_[qq] += e;
            }
        }
        // ---- PV: V from global (L2-resident), lane's 16 channels, 4 queries ----
        #pragma unroll
        for (int mm = 0; mm < 8; ++mm) {
            const int m = (blk << 6) | (mm << 3) | j;
            #pragma unroll
            for (int i = 0; i < 4; ++i) {
                const float4 vv = Vg[(i << 10) + m];
                #pragma unroll
                for (int qq = 0; qq < 4; ++qq) {
                    const float e = s[qq][mm];
                    acc[qq][4*i+0] = fmaf(e, vv.x, acc[qq][4*i+0]);
                    acc[qq][4*i+1] = fmaf(e, vv.y, acc[qq][4*i+1]);
                    acc[qq][4*i+2] = fmaf(e, vv.z, acc[qq][4*i+2]);
                    acc[qq][4*i+3] = fmaf(e, vv.w, acc[qq][4*i+3]);
                }
            }
        }
    }

    // ---- merge across j (xor 1,2,4); h-halves hold identical m/l ----
    #pragma unroll
    for (int qq = 0; qq < 4; ++qq) {
        float M = m_[qq];
        M = fmaxf(M, __shfl_xor(M, 1)); M = fmaxf(M, __shfl_xor(M, 2)); M = fmaxf(M, __shfl_xor(M, 4));
        float a = __expf(m_[qq] - M);
        float lv = l_[qq] * a;
        lv += __shfl_xor(lv, 1); lv += __shfl_xor(lv, 2); lv += __shfl_xor(lv, 4);
        l_[qq] = lv;
        #pragma unroll
        for (int cc = 0; cc < 16; ++cc) {
            float v = acc[qq][cc] * a;
            v += __shfl_xor(v, 1); v += __shfl_xor(v, 2); v += __shfl_xor(v, 4);
            acc[qq][cc] = v;
        }
    }

    // ---- exchange via LDS — STATIC indices, exec-mask predication ----
    #pragma unroll
    for (int qq = 0; qq < 4; ++qq) {
        if (j == qq) {
            float* dst = &Gsh[(grp * 4 + qq) * 36 + h * 16];
            ((float4*)dst)[0] = make_float4(acc[qq][0],  acc[qq][1],  acc[qq][2],  acc[qq][3]);
            ((float4*)dst)[1] = make_float4(acc[qq][4],  acc[qq][5],  acc[qq][6],  acc[qq][7]);
            ((float4*)dst)[2] = make_float4(acc[qq][8],  acc[qq][9],  acc[qq][10], acc[qq][11]);
            ((float4*)dst)[3] = make_float4(acc[qq][12], acc[qq][13], acc[qq][14], acc[qq][15]);
            if (h == 0) Gsh[(grp * 4 + qq) * 36 + 32] = l_[qq];
        }
    }
    __syncthreads();

    // ---- epilogue: thread (q=tid>>2, r=tid&3) handles o ≡ r (mod 4) ----
    {
        const int q = tid >> 2, r = tid & 3;
        const float rL = 1.0f / Gsh[q * 36 + 32];
        const float4* gq4 = (const float4*)&Gsh[q * 36];
        float g[32];
        #pragma unroll
        for (int i = 0; i < 8; ++i) {
            const float4 gv = gq4[i];
            g[4*i+0] = gv.x * rL; g[4*i+1] = gv.y * rL;
            g[4*i+2] = gv.z * rL; g[4*i+3] = gv.w * rL;
        }

        const int n = (tile << 6) + q;
        const float* xp = x + (size_t)b * (CHn * HWn) + n;
        float* op = out + (size_t)b * (CHn * HWn) + n;

        #pragma unroll
        for (int oo = 0; oo < 16; ++oo) {
            const int o = (oo << 2) | r;
            const float4* wr = (const float4*)&wpf[o * 36];
            float po = pbeta[o];
            #pragma unroll
            for (int c4 = 0; c4 < 8; ++c4) {
                const float4 w = wr[c4];
                po += w.x * g[4*c4] + w.y * g[4*c4+1] + w.z * g[4*c4+2] + w.w * g[4*c4+3];
            }
            op[o * HWn] = xp[o * HWn] + po;
        }
    }
}

// ------------------------------- launcher ------------------------------------
extern "C" void kernel_launch(void* const* d_in, const int* in_sizes, int n_in,
                              void* d_out, int out_size, void* d_ws, size_t ws_size,
                              hipStream_t stream)
{
    const float* x    = (const float*)d_in[0];
    const float* mem  = (const float*)d_in[1];
    const float* wq   = (const float*)d_in[2];
    const float* bq   = (const float*)d_in[3];
    const float* bnqs = (const float*)d_in[4];
    const float* bnqb = (const float*)d_in[5];
    const float* bnqm = (const float*)d_in[6];
    const float* bnqv = (const float*)d_in[7];
    const float* wk   = (const float*)d_in[8];
    const float* bk   = (const float*)d_in[9];
    const float* bnks = (const float*)d_in[10];
    const float* bnkb = (const float*)d_in[11];
    const float* bnkm = (const float*)d_in[12];
    const float* bnkv = (const float*)d_in[13];
    const float* wv   = (const float*)d_in[14];
    const float* bv   = (const float*)d_in[15];
    const float* bnvs = (const float*)d_in[16];
    const float* bnvb = (const float*)d_in[17];
    const float* bnvm = (const float*)d_in[18];
    const float* bnvv = (const float*)d_in[19];
    const float* wp   = (const float*)d_in[20];
    const float* bp   = (const float*)d_in[21];
    const float* bnps = (const float*)d_in[22];
    const float* bnpb = (const float*)d_in[23];
    const float* bnpm = (const float*)d_in[24];
    const float* bnpv = (const float*)d_in[25];
    const float* gam  = (const float*)d_in[26];

    (void)d_ws; (void)ws_size; (void)in_sizes; (void)n_in; (void)out_size;

    k_proj_kv<<<dim3(256), dim3(192), 0, stream>>>(mem,
        wk, bk, bnks, bnkb, bnkm, bnkv,
        wv, bv, bnvs, bnvb, bnvm, bnvv);
    k_attn5<<<dim3(512), dim3(256), 0, stream>>>(mem, x,
        wq, bq, bnqs, bnqb, bnqm, bnqv,
        wp, bp, bnps, bnpb, bnpm, bnpv, gam,
        (float*)d_out);
}

// Round 9
// 159.913 us; speedup vs baseline: 1.5199x; 1.4315x over previous
//
#include <hip/hip_runtime.h>

#define EPS_BN 1e-5f

// Problem constants: B=8, CH=64, H=W=64  (all I/O float32)
constexpr int Bn   = 8;
constexpr int CHn  = 64;
constexpr int HWn  = 4096;   // 64*64
constexpr int HW4n = 1024;   // pooled keys
constexpr int CQn  = 8;      // CH/8
constexpr int CVn  = 32;     // CH/2

typedef short bf16x8 __attribute__((ext_vector_type(8)));
typedef float f32x4  __attribute__((ext_vector_type(4)));

union FragI { int4 i; bf16x8 v; };

__device__ __forceinline__ unsigned short f2bf(float f) {
    unsigned u = __float_as_uint(f);
    unsigned r = u + 0x7FFFu + ((u >> 16) & 1u);
    return (unsigned short)(r >> 16);
}
__device__ __forceinline__ float bf2f(unsigned short h) {
    return __uint_as_float(((unsigned)h) << 16);
}

// Module-scope scratch; fully rewritten every call.
__device__ __align__(16) short g_Kh[Bn * HW4n * CQn];   // K hi bf16 [b][m][8]
__device__ __align__(16) short g_Kl[Bn * HW4n * CQn];   // K lo bf16 [b][m][8]
__device__ __align__(16) short g_Vt[Bn * CVn * HW4n];   // V^T bf16 [b][ch][key]

// ------------- Kernel A: K,V projection + BN + 2x2 maxpool -------------------
// 256 blocks x 192 threads. Block = one pooled row (32 pooled px) of one batch.
__global__ __launch_bounds__(192)
void k_proj_kv(const float* __restrict__ mem,
               const float* __restrict__ wk,  const float* __restrict__ bk,
               const float* __restrict__ ks,  const float* __restrict__ kb,
               const float* __restrict__ km,  const float* __restrict__ kv,
               const float* __restrict__ wv,  const float* __restrict__ bv_,
               const float* __restrict__ vs,  const float* __restrict__ vb,
               const float* __restrict__ vm,  const float* __restrict__ vv)
{
    __shared__ float wall[2560];   // [ch][40]: c 0..7 = K, 8..39 = V (BN folded)
    __shared__ float beta[40];
    __shared__ float Msh[8192];    // [ch][32 quads][4 px], 32 KB

    const int tid = threadIdx.x;
    for (int idx = tid; idx < 2560; idx += 192) {
        int c = idx % 40, ch = idx / 40;
        float w, inv;
        if (c < 8) { inv = ks[c] * rsqrtf(kv[c] + EPS_BN); w = wk[c * 64 + ch]; }
        else { int c2 = c - 8; inv = vs[c2] * rsqrtf(vv[c2] + EPS_BN); w = wv[c2 * 64 + ch]; }
        wall[ch * 40 + c] = w * inv;
    }
    if (tid < 40) {
        int c = tid;
        if (c < 8) {
            float inv = ks[c] * rsqrtf(kv[c] + EPS_BN);
            beta[c] = (bk[c] - km[c]) * inv + kb[c];
        } else {
            int c2 = c - 8;
            float inv = vs[c2] * rsqrtf(vv[c2] + EPS_BN);
            beta[c] = (bv_[c2] - vm[c2]) * inv + vb[c2];
        }
    }

    const int b = blockIdx.x >> 5;        // 32 blocks per batch
    const int R = blockIdx.x & 31;        // pooled row

    {
        const float* src = mem + (size_t)b * (CHn * HWn) + (R << 7);
        for (int idx = tid; idx < 4096; idx += 192) {
            int ch = idx >> 6, p2 = idx & 63;
            float2 v = *(const float2*)(src + ch * HWn + (p2 << 1));
            int r = p2 >> 5, w2 = p2 & 31;
            *(float2*)&Msh[ch * 128 + (w2 << 2) + (r << 1)] = v;
        }
    }
    __syncthreads();

    if (tid < 160) {
        const int g  = tid % 5;        // 0 = K(8ch), 1..4 = V 8ch each
        const int qd = tid / 5;        // pooled col 0..31
        float acc[4][8];
        #pragma unroll
        for (int p = 0; p < 4; ++p)
            #pragma unroll
            for (int c = 0; c < 8; ++c) acc[p][c] = 0.f;

        for (int ch = 0; ch < 64; ++ch) {
            const float4 mq = *(const float4*)&Msh[ch * 128 + (qd << 2)];
            const float4* wr = (const float4*)&wall[ch * 40 + (g << 3)];
            const float4 w0 = wr[0], w1 = wr[1];
            #pragma unroll
            for (int p = 0; p < 4; ++p) {
                const float mv = (p == 0) ? mq.x : (p == 1) ? mq.y : (p == 2) ? mq.z : mq.w;
                acc[p][0] = fmaf(w0.x, mv, acc[p][0]); acc[p][1] = fmaf(w0.y, mv, acc[p][1]);
                acc[p][2] = fmaf(w0.z, mv, acc[p][2]); acc[p][3] = fmaf(w0.w, mv, acc[p][3]);
                acc[p][4] = fmaf(w1.x, mv, acc[p][4]); acc[p][5] = fmaf(w1.y, mv, acc[p][5]);
                acc[p][6] = fmaf(w1.z, mv, acc[p][6]); acc[p][7] = fmaf(w1.w, mv, acc[p][7]);
            }
        }
        float o[8];
        #pragma unroll
        for (int c = 0; c < 8; ++c)
            o[c] = fmaxf(fmaxf(acc[0][c], acc[1][c]), fmaxf(acc[2][c], acc[3][c]))
                 + beta[(g << 3) + c];

        const int m = (R << 5) + qd;
        if (g == 0) {
            // K row -> hi/lo bf16
            unsigned short hb[8], lb[8];
            #pragma unroll
            for (int c = 0; c < 8; ++c) {
                hb[c] = f2bf(o[c]);
                lb[c] = f2bf(o[c] - bf2f(hb[c]));
            }
            int4 hi4 = make_int4((int)(hb[0] | ((unsigned)hb[1] << 16)),
                                 (int)(hb[2] | ((unsigned)hb[3] << 16)),
                                 (int)(hb[4] | ((unsigned)hb[5] << 16)),
                                 (int)(hb[6] | ((unsigned)hb[7] << 16)));
            int4 lo4 = make_int4((int)(lb[0] | ((unsigned)lb[1] << 16)),
                                 (int)(lb[2] | ((unsigned)lb[3] << 16)),
                                 (int)(lb[4] | ((unsigned)lb[5] << 16)),
                                 (int)(lb[6] | ((unsigned)lb[7] << 16)));
            *(int4*)&g_Kh[((size_t)b * HW4n + m) * CQn] = hi4;
            *(int4*)&g_Kl[((size_t)b * HW4n + m) * CQn] = lo4;
        } else {
            // V^T bf16: [b][ch][key]
            const int ch0 = (g - 1) << 3;
            #pragma unroll
            for (int c = 0; c < 8; ++c)
                g_Vt[(size_t)b * (CVn * HW4n) + (ch0 + c) * HW4n + m] = (short)f2bf(o[c]);
        }
    }
}

// ------ Kernel B: MFMA flash attention (Q-proj + softmax + PV + out-proj) ----
// 512 blocks x 256 threads (4 waves). Wave = 16 queries. S^T orientation:
// QK mfma gives rows=keys, cols=queries; PV mfma gives rows=queries, cols=ch.
// K resident in LDS (bf16 hi/lo); V^T streamed in 4 x 256-key bf16 chunks.
__global__ __launch_bounds__(256, 2)
void k_attn6(const float* __restrict__ mem,
             const float* __restrict__ x,
             const float* __restrict__ wq, const float* __restrict__ bq,
             const float* __restrict__ qs, const float* __restrict__ qb,
             const float* __restrict__ qm, const float* __restrict__ qv,
             const float* __restrict__ wp, const float* __restrict__ bp,
             const float* __restrict__ ps, const float* __restrict__ pb,
             const float* __restrict__ pm, const float* __restrict__ pv,
             const float* __restrict__ gamma,
             float* __restrict__ out)
{
    __shared__ __align__(16) short Kh_sh[HW4n * CQn];   // 16 KB
    __shared__ __align__(16) short Kl_sh[HW4n * CQn];   // 16 KB
    __shared__ __align__(16) short Vt_sh[32 * 264];     // 16.9 KB (chunk, pitch 264)
    __shared__ __align__(16) short Psh[4 * 16 * 40];    // 5 KB (per-wave P tiles)
    __shared__ __align__(16) float qw_sh[512];          // folded Q weights [ch][8]
    __shared__ float qbeta_sh[8];
    __shared__ float pbeta_sh[64];

    const int tid  = threadIdx.x;
    const int lane = tid & 63;
    const int w    = tid >> 6;           // wave 0..3
    const int quad = lane >> 4;          // 0..3
    const int c    = lane & 15;          // col lane
    const int b    = blockIdx.x >> 6;    // 64 tiles per batch
    const int tile = blockIdx.x & 63;
    const float gm = gamma[0];

    // ---- stage folded Q weights + biases ----
    for (int idx = tid; idx < 512; idx += 256) {
        int cc = idx & 7, ch = idx >> 3;
        float inv = qs[cc] * rsqrtf(qv[cc] + EPS_BN);
        qw_sh[ch * 8 + cc] = wq[cc * 64 + ch] * inv;
    }
    if (tid < 8) {
        float inv = qs[tid] * rsqrtf(qv[tid] + EPS_BN);
        qbeta_sh[tid] = (bq[tid] - qm[tid]) * inv + qb[tid];
    }
    if (tid < 64) {
        float inv = ps[tid] * rsqrtf(pv[tid] + EPS_BN);
        pbeta_sh[tid] = gm * ((bp[tid] - pm[tid]) * inv + pb[tid]);
    }
    // ---- stage K hi/lo (16 KB each) + V^T chunk 0 ----
    {
        const int4* Kh4 = (const int4*)(g_Kh + (size_t)b * (HW4n * CQn));
        const int4* Kl4 = (const int4*)(g_Kl + (size_t)b * (HW4n * CQn));
        int4* dh = (int4*)Kh_sh;
        int4* dl = (int4*)Kl_sh;
        #pragma unroll
        for (int i = 0; i < 4; ++i) {
            dh[tid + i * 256] = Kh4[tid + i * 256];
            dl[tid + i * 256] = Kl4[tid + i * 256];
        }
        const short* Vsrc = g_Vt + (size_t)b * (CVn * HW4n);
        #pragma unroll
        for (int i = 0; i < 4; ++i) {
            int idx4 = tid + i * 256;
            int ch = idx4 >> 5, ko = (idx4 & 31) << 3;
            *(int4*)&Vt_sh[ch * 264 + ko] = *(const int4*)(Vsrc + ch * HW4n + ko);
        }
    }
    __syncthreads();

    // ---- Q projection: lane computes q for query (tile*64 + w*16 + c) ----
    float q0 = 0.f, q1 = 0.f, q2 = 0.f, q3 = 0.f, q4 = 0.f, q5 = 0.f, q6 = 0.f, q7 = 0.f;
    {
        const float* mp = mem + (size_t)b * (CHn * HWn) + (tile << 6) + (w << 4) + c;
        #pragma unroll
        for (int cc = 0; cc < 16; ++cc) {
            const int ch = (quad << 4) | cc;
            const float mv = mp[ch * HWn];
            const float4 w0 = *(const float4*)&qw_sh[ch * 8];
            const float4 w1 = *(const float4*)&qw_sh[ch * 8 + 4];
            q0 = fmaf(w0.x, mv, q0); q1 = fmaf(w0.y, mv, q1);
            q2 = fmaf(w0.z, mv, q2); q3 = fmaf(w0.w, mv, q3);
            q4 = fmaf(w1.x, mv, q4); q5 = fmaf(w1.y, mv, q5);
            q6 = fmaf(w1.z, mv, q6); q7 = fmaf(w1.w, mv, q7);
        }
        q0 += __shfl_xor(q0, 16); q0 += __shfl_xor(q0, 32); q0 += qbeta_sh[0];
        q1 += __shfl_xor(q1, 16); q1 += __shfl_xor(q1, 32); q1 += qbeta_sh[1];
        q2 += __shfl_xor(q2, 16); q2 += __shfl_xor(q2, 32); q2 += qbeta_sh[2];
        q3 += __shfl_xor(q3, 16); q3 += __shfl_xor(q3, 32); q3 += qbeta_sh[3];
        q4 += __shfl_xor(q4, 16); q4 += __shfl_xor(q4, 32); q4 += qbeta_sh[4];
        q5 += __shfl_xor(q5, 16); q5 += __shfl_xor(q5, 32); q5 += qbeta_sh[5];
        q6 += __shfl_xor(q6, 16); q6 += __shfl_xor(q6, 32); q6 += qbeta_sh[6];
        q7 += __shfl_xor(q7, 16); q7 += __shfl_xor(q7, 32); q7 += qbeta_sh[7];
    }
    // B-frags for QK (Q^T): quad 0 carries dims 0..7 (hi & lo); quads 1-3 zero.
    bf16x8 bqh, bql;
    {
        unsigned short h0 = f2bf(q0), h1 = f2bf(q1), h2 = f2bf(q2), h3 = f2bf(q3);
        unsigned short h4 = f2bf(q4), h5 = f2bf(q5), h6 = f2bf(q6), h7 = f2bf(q7);
        unsigned short l0 = f2bf(q0 - bf2f(h0)), l1 = f2bf(q1 - bf2f(h1));
        unsigned short l2 = f2bf(q2 - bf2f(h2)), l3 = f2bf(q3 - bf2f(h3));
        unsigned short l4 = f2bf(q4 - bf2f(h4)), l5 = f2bf(q5 - bf2f(h5));
        unsigned short l6 = f2bf(q6 - bf2f(h6)), l7 = f2bf(q7 - bf2f(h7));
        FragI fh, fl;
        fh.i = make_int4((int)(h0 | ((unsigned)h1 << 16)), (int)(h2 | ((unsigned)h3 << 16)),
                         (int)(h4 | ((unsigned)h5 << 16)), (int)(h6 | ((unsigned)h7 << 16)));
        fl.i = make_int4((int)(l0 | ((unsigned)l1 << 16)), (int)(l2 | ((unsigned)l3 << 16)),
                         (int)(l4 | ((unsigned)l5 << 16)), (int)(l6 | ((unsigned)l7 << 16)));
        FragI fz; fz.i = make_int4(0, 0, 0, 0);
        bqh = (quad == 0) ? fh.v : fz.v;
        bql = (quad == 0) ? fl.v : fz.v;
    }

    // ---- online-softmax state ----
    f32x4 acc0 = {0.f, 0.f, 0.f, 0.f};   // rows=queries 4q+reg, cols=ch c
    f32x4 acc1 = {0.f, 0.f, 0.f, 0.f};   // cols=ch 16+c
    float m_ = -3.0e38f, l_ = 0.f;

    const int pbase = w * 640 + c * 40;           // this lane's P row (query c)
    const int pread = w * 640 + c * 40 + (quad << 3);

    for (int chunk = 0; chunk < 4; ++chunk) {
        if (chunk) {
            __syncthreads();
            const short* Vsrc = g_Vt + (size_t)b * (CVn * HW4n) + (chunk << 8);
            #pragma unroll
            for (int i = 0; i < 4; ++i) {
                int idx4 = tid + i * 256;
                int ch = idx4 >> 5, ko = (idx4 & 31) << 3;
                *(int4*)&Vt_sh[ch * 264 + ko] = *(const int4*)(Vsrc + ch * HW4n + ko);
            }
            __syncthreads();
        }
        for (int st = 0; st < 8; ++st) {
            const int kb   = (chunk << 8) + (st << 5);   // global key base
            const int kloc = st << 5;                     // chunk-local base

            // ---- QK scores (S^T): two 16-key substeps, hi/lo 3-mfma each ----
            f32x4 sa = {0.f, 0.f, 0.f, 0.f};
            f32x4 sb = {0.f, 0.f, 0.f, 0.f};
            {
                const bf16x8 ah0 = *(const bf16x8*)&Kh_sh[(kb + c) * 8];
                const bf16x8 al0 = *(const bf16x8*)&Kl_sh[(kb + c) * 8];
                sa = __builtin_amdgcn_mfma_f32_16x16x32_bf16(ah0, bqh, sa, 0, 0, 0);
                sa = __builtin_amdgcn_mfma_f32_16x16x32_bf16(ah0, bql, sa, 0, 0, 0);
                sa = __builtin_amdgcn_mfma_f32_16x16x32_bf16(al0, bqh, sa, 0, 0, 0);
                const bf16x8 ah1 = *(const bf16x8*)&Kh_sh[(kb + 16 + c) * 8];
                const bf16x8 al1 = *(const bf16x8*)&Kl_sh[(kb + 16 + c) * 8];
                sb = __builtin_amdgcn_mfma_f32_16x16x32_bf16(ah1, bqh, sb, 0, 0, 0);
                sb = __builtin_amdgcn_mfma_f32_16x16x32_bf16(ah1, bql, sb, 0, 0, 0);
                sb = __builtin_amdgcn_mfma_f32_16x16x32_bf16(al1, bqh, sb, 0, 0, 0);
            }

            // ---- online softmax (rows=keys; col c = query) ----
            float mx = fmaxf(fmaxf(fmaxf(sa[0], sa[1]), fmaxf(sa[2], sa[3])),
                             fmaxf(fmaxf(sb[0], sb[1]), fmaxf(sb[2], sb[3])));
            mx = fmaxf(mx, m_);
            mx = fmaxf(mx, __shfl_xor(mx, 16));
            mx = fmaxf(mx, __shfl_xor(mx, 32));
            const float alpha = __expf(m_ - mx);
            m_ = mx;
            const float pa0 = __expf(sa[0] - mx), pa1 = __expf(sa[1] - mx);
            const float pa2 = __expf(sa[2] - mx), pa3 = __expf(sa[3] - mx);
            const float pb0 = __expf(sb[0] - mx), pb1 = __expf(sb[1] - mx);
            const float pb2 = __expf(sb[2] - mx), pb3 = __expf(sb[3] - mx);
            l_ = l_ * alpha + (pa0 + pa1 + pa2 + pa3 + pb0 + pb1 + pb2 + pb3);

            // ---- write P (bf16, packed pairs) into per-wave tile ----
            *(int*)&Psh[pbase + (quad << 2)]          = (int)(f2bf(pa0) | ((unsigned)f2bf(pa1) << 16));
            *(int*)&Psh[pbase + (quad << 2) + 2]      = (int)(f2bf(pa2) | ((unsigned)f2bf(pa3) << 16));
            *(int*)&Psh[pbase + 16 + (quad << 2)]     = (int)(f2bf(pb0) | ((unsigned)f2bf(pb1) << 16));
            *(int*)&Psh[pbase + 16 + (quad << 2) + 2] = (int)(f2bf(pb2) | ((unsigned)f2bf(pb3) << 16));

            // ---- rescale acc by alpha of its row-queries (4q+r) ----
            const float a0 = __shfl(alpha, 20 * quad + 0);
            const float a1 = __shfl(alpha, 20 * quad + 1);
            const float a2 = __shfl(alpha, 20 * quad + 2);
            const float a3 = __shfl(alpha, 20 * quad + 3);
            acc0[0] *= a0; acc0[1] *= a1; acc0[2] *= a2; acc0[3] *= a3;
            acc1[0] *= a0; acc1[1] *= a1; acc1[2] *= a2; acc1[3] *= a3;

            // ---- PV: A = P[query][key0..31], B = V^T[key][ch] ----
            const bf16x8 pfrag = *(const bf16x8*)&Psh[pread];
            const bf16x8 v0 = *(const bf16x8*)&Vt_sh[c * 264 + kloc + (quad << 3)];
            const bf16x8 v1 = *(const bf16x8*)&Vt_sh[(16 + c) * 264 + kloc + (quad << 3)];
            acc0 = __builtin_amdgcn_mfma_f32_16x16x32_bf16(pfrag, v0, acc0, 0, 0, 0);
            acc1 = __builtin_amdgcn_mfma_f32_16x16x32_bf16(pfrag, v1, acc1, 0, 0, 0);
        }
    }

    __syncthreads();   // all waves done with Kh/Vt

    // ---- stage folded out-proj weights into Vt region (overlay) ----
    float* wpf = (float*)Vt_sh;            // [o][36-pitch]
    for (int idx = tid; idx < 2048; idx += 256) {
        int o = idx >> 5, cc = idx & 31;
        float inv = ps[o] * rsqrtf(pv[o] + EPS_BN);
        wpf[o * 36 + cc] = wp[o * 32 + cc] * inv * gm;
    }

    // ---- finalize l, normalize, write g to Gsh (overlay on Kh) ----
    {
        l_ += __shfl_xor(l_, 16);
        l_ += __shfl_xor(l_, 32);
        const float rl = 1.0f / l_;
        const float r0 = __shfl(rl, 20 * quad + 0);
        const float r1 = __shfl(rl, 20 * quad + 1);
        const float r2 = __shfl(rl, 20 * quad + 2);
        const float r3 = __shfl(rl, 20 * quad + 3);
        float* Gsh = (float*)Kh_sh;        // [64 q][36-pitch]
        const int row = (w << 4) + (quad << 2);
        Gsh[(row + 0) * 36 + c] = acc0[0] * r0;
        Gsh[(row + 1) * 36 + c] = acc0[1] * r1;
        Gsh[(row + 2) * 36 + c] = acc0[2] * r2;
        Gsh[(row + 3) * 36 + c] = acc0[3] * r3;
        Gsh[(row + 0) * 36 + 16 + c] = acc1[0] * r0;
        Gsh[(row + 1) * 36 + 16 + c] = acc1[1] * r1;
        Gsh[(row + 2) * 36 + 16 + c] = acc1[2] * r2;
        Gsh[(row + 3) * 36 + 16 + c] = acc1[3] * r3;
    }
    __syncthreads();

    // ---- epilogue: thread (q=tid>>2, r=tid&3) handles o ≡ r (mod 4) ----
    {
        const float* Gsh = (const float*)Kh_sh;
        const int q = tid >> 2, r = tid & 3;
        const float4* gq4 = (const float4*)&Gsh[q * 36];
        float g[32];
        #pragma unroll
        for (int i = 0; i < 8; ++i) {
            const float4 gv = gq4[i];
            g[4*i+0] = gv.x; g[4*i+1] = gv.y; g[4*i+2] = gv.z; g[4*i+3] = gv.w;
        }
        const int n = (tile << 6) + q;
        const float* xp = x + (size_t)b * (CHn * HWn) + n;
        float* op = out + (size_t)b * (CHn * HWn) + n;

        #pragma unroll
        for (int oo = 0; oo < 16; ++oo) {
            const int o = (oo << 2) | r;
            const float4* wr = (const float4*)&wpf[o * 36];
            float po = pbeta_sh[o];
            #pragma unroll
            for (int c4 = 0; c4 < 8; ++c4) {
                const float4 ww = wr[c4];
                po += ww.x * g[4*c4] + ww.y * g[4*c4+1] + ww.z * g[4*c4+2] + ww.w * g[4*c4+3];
            }
            op[o * HWn] = xp[o * HWn] + po;
        }
    }
}

// ------------------------------- launcher ------------------------------------
extern "C" void kernel_launch(void* const* d_in, const int* in_sizes, int n_in,
                              void* d_out, int out_size, void* d_ws, size_t ws_size,
                              hipStream_t stream)
{
    const float* x    = (const float*)d_in[0];
    const float* mem  = (const float*)d_in[1];
    const float* wq   = (const float*)d_in[2];
    const float* bq   = (const float*)d_in[3];
    const float* bnqs = (const float*)d_in[4];
    const float* bnqb = (const float*)d_in[5];
    const float* bnqm = (const float*)d_in[6];
    const float* bnqv = (const float*)d_in[7];
    const float* wk   = (const float*)d_in[8];
    const float* bk   = (const float*)d_in[9];
    const float* bnks = (const float*)d_in[10];
    const float* bnkb = (const float*)d_in[11];
    const float* bnkm = (const float*)d_in[12];
    const float* bnkv = (const float*)d_in[13];
    const float* wv   = (const float*)d_in[14];
    const float* bv   = (const float*)d_in[15];
    const float* bnvs = (const float*)d_in[16];
    const float* bnvb = (const float*)d_in[17];
    const float* bnvm = (const float*)d_in[18];
    const float* bnvv = (const float*)d_in[19];
    const float* wp   = (const float*)d_in[20];
    const float* bp   = (const float*)d_in[21];
    const float* bnps = (const float*)d_in[22];
    const float* bnpb = (const float*)d_in[23];
    const float* bnpm = (const float*)d_in[24];
    const float* bnpv = (const float*)d_in[25];
    const float* gam  = (const float*)d_in[26];

    (void)d_ws; (void)ws_size; (void)in_sizes; (void)n_in; (void)out_size;

    k_proj_kv<<<dim3(256), dim3(192), 0, stream>>>(mem,
        wk, bk, bnks, bnkb, bnkm, bnkv,
        wv, bv, bnvs, bnvb, bnvm, bnvv);
    k_attn6<<<dim3(512), dim3(256), 0, stream>>>(mem, x,
        wq, bq, bnqs, bnqb, bnqm, bnqv,
        wp, bp, bnps, bnpb, bnpm, bnpv, gam,
        (float*)d_out);
}

// Round 10
// 154.396 us; speedup vs baseline: 1.5742x; 1.0357x over previous
//
#include <hip/hip_runtime.h>

#define EPS_BN 1e-5f

// Problem constants: B=8, CH=64, H=W=64  (all I/O float32)
constexpr int Bn   = 8;
constexpr int CHn  = 64;
constexpr int HWn  = 4096;   // 64*64
constexpr int HW4n = 1024;   // pooled keys
constexpr int CQn  = 8;      // CH/8
constexpr int CVn  = 32;     // CH/2

typedef short bf16x8 __attribute__((ext_vector_type(8)));
typedef float f32x4  __attribute__((ext_vector_type(4)));

union FragI { int4 i; bf16x8 v; };

__device__ __forceinline__ unsigned short f2bf(float f) {
    unsigned u = __float_as_uint(f);
    unsigned r = u + 0x7FFFu + ((u >> 16) & 1u);
    return (unsigned short)(r >> 16);
}
__device__ __forceinline__ float bf2f(unsigned short h) {
    return __uint_as_float(((unsigned)h) << 16);
}

// Module-scope scratch; fully rewritten every call.
__device__ __align__(16) short g_Kh[Bn * HW4n * CQn];   // K hi bf16 [b][m][8]
__device__ __align__(16) short g_Kl[Bn * HW4n * CQn];   // K lo bf16 [b][m][8]
__device__ __align__(16) short g_Vt[Bn * CVn * HW4n];   // V^T bf16 [b][ch][key]

// ------------- Kernel A: K,V projection + BN + 2x2 maxpool -------------------
// 256 blocks x 192 threads. Block = one pooled row (32 pooled px) of one batch.
__global__ __launch_bounds__(192)
void k_proj_kv(const float* __restrict__ mem,
               const float* __restrict__ wk,  const float* __restrict__ bk,
               const float* __restrict__ ks,  const float* __restrict__ kb,
               const float* __restrict__ km,  const float* __restrict__ kv,
               const float* __restrict__ wv,  const float* __restrict__ bv_,
               const float* __restrict__ vs,  const float* __restrict__ vb,
               const float* __restrict__ vm,  const float* __restrict__ vv)
{
    __shared__ float wall[2560];   // [ch][40]: c 0..7 = K, 8..39 = V (BN folded)
    __shared__ float beta[40];
    __shared__ float Msh[8192];    // [ch][32 quads][4 px], 32 KB

    const int tid = threadIdx.x;
    for (int idx = tid; idx < 2560; idx += 192) {
        int c = idx % 40, ch = idx / 40;
        float w, inv;
        if (c < 8) { inv = ks[c] * rsqrtf(kv[c] + EPS_BN); w = wk[c * 64 + ch]; }
        else { int c2 = c - 8; inv = vs[c2] * rsqrtf(vv[c2] + EPS_BN); w = wv[c2 * 64 + ch]; }
        wall[ch * 40 + c] = w * inv;
    }
    if (tid < 40) {
        int c = tid;
        if (c < 8) {
            float inv = ks[c] * rsqrtf(kv[c] + EPS_BN);
            beta[c] = (bk[c] - km[c]) * inv + kb[c];
        } else {
            int c2 = c - 8;
            float inv = vs[c2] * rsqrtf(vv[c2] + EPS_BN);
            beta[c] = (bv_[c2] - vm[c2]) * inv + vb[c2];
        }
    }

    const int b = blockIdx.x >> 5;        // 32 blocks per batch
    const int R = blockIdx.x & 31;        // pooled row

    {
        const float* src = mem + (size_t)b * (CHn * HWn) + (R << 7);
        for (int idx = tid; idx < 4096; idx += 192) {
            int ch = idx >> 6, p2 = idx & 63;
            float2 v = *(const float2*)(src + ch * HWn + (p2 << 1));
            int r = p2 >> 5, w2 = p2 & 31;
            *(float2*)&Msh[ch * 128 + (w2 << 2) + (r << 1)] = v;
        }
    }
    __syncthreads();

    if (tid < 160) {
        const int g  = tid % 5;        // 0 = K(8ch), 1..4 = V 8ch each
        const int qd = tid / 5;        // pooled col 0..31
        float acc[4][8];
        #pragma unroll
        for (int p = 0; p < 4; ++p)
            #pragma unroll
            for (int c = 0; c < 8; ++c) acc[p][c] = 0.f;

        for (int ch = 0; ch < 64; ++ch) {
            const float4 mq = *(const float4*)&Msh[ch * 128 + (qd << 2)];
            const float4* wr = (const float4*)&wall[ch * 40 + (g << 3)];
            const float4 w0 = wr[0], w1 = wr[1];
            #pragma unroll
            for (int p = 0; p < 4; ++p) {
                const float mv = (p == 0) ? mq.x : (p == 1) ? mq.y : (p == 2) ? mq.z : mq.w;
                acc[p][0] = fmaf(w0.x, mv, acc[p][0]); acc[p][1] = fmaf(w0.y, mv, acc[p][1]);
                acc[p][2] = fmaf(w0.z, mv, acc[p][2]); acc[p][3] = fmaf(w0.w, mv, acc[p][3]);
                acc[p][4] = fmaf(w1.x, mv, acc[p][4]); acc[p][5] = fmaf(w1.y, mv, acc[p][5]);
                acc[p][6] = fmaf(w1.z, mv, acc[p][6]); acc[p][7] = fmaf(w1.w, mv, acc[p][7]);
            }
        }
        float o[8];
        #pragma unroll
        for (int c = 0; c < 8; ++c)
            o[c] = fmaxf(fmaxf(acc[0][c], acc[1][c]), fmaxf(acc[2][c], acc[3][c]))
                 + beta[(g << 3) + c];

        const int m = (R << 5) + qd;
        if (g == 0) {
            unsigned short hb[8], lb[8];
            #pragma unroll
            for (int c = 0; c < 8; ++c) {
                hb[c] = f2bf(o[c]);
                lb[c] = f2bf(o[c] - bf2f(hb[c]));
            }
            int4 hi4 = make_int4((int)(hb[0] | ((unsigned)hb[1] << 16)),
                                 (int)(hb[2] | ((unsigned)hb[3] << 16)),
                                 (int)(hb[4] | ((unsigned)hb[5] << 16)),
                                 (int)(hb[6] | ((unsigned)hb[7] << 16)));
            int4 lo4 = make_int4((int)(lb[0] | ((unsigned)lb[1] << 16)),
                                 (int)(lb[2] | ((unsigned)lb[3] << 16)),
                                 (int)(lb[4] | ((unsigned)lb[5] << 16)),
                                 (int)(lb[6] | ((unsigned)lb[7] << 16)));
            *(int4*)&g_Kh[((size_t)b * HW4n + m) * CQn] = hi4;
            *(int4*)&g_Kl[((size_t)b * HW4n + m) * CQn] = lo4;
        } else {
            const int ch0 = (g - 1) << 3;
            #pragma unroll
            for (int c = 0; c < 8; ++c)
                g_Vt[(size_t)b * (CVn * HW4n) + (ch0 + c) * HW4n + m] = (short)f2bf(o[c]);
        }
    }
}

// ------ Kernel B: MFMA flash attention, single-mfma hi/lo QK -----------------
// 512 blocks x 256 threads (4 waves). Wave = 16 queries, S^T orientation.
// QK: A = [Khi,Khi,Klo,Klo] (per-quad row select), B = [Qhi,Qlo,Qhi,Qlo]
// -> ONE 16x16x32 mfma computes the full hi/lo product per 16-key half.
// P double-buffered (step parity); V^T double-buffered 128-key chunks,
// prefetch-then-barrier (1 barrier/chunk).
__global__ __launch_bounds__(256, 2) __attribute__((amdgpu_waves_per_eu(2, 2)))
void k_attn7(const float* __restrict__ mem,
             const float* __restrict__ x,
             const float* __restrict__ wq, const float* __restrict__ bq,
             const float* __restrict__ qs, const float* __restrict__ qb,
             const float* __restrict__ qm, const float* __restrict__ qv,
             const float* __restrict__ wp, const float* __restrict__ bp,
             const float* __restrict__ ps, const float* __restrict__ pb,
             const float* __restrict__ pm, const float* __restrict__ pv,
             const float* __restrict__ gamma,
             float* __restrict__ out)
{
    __shared__ __align__(16) short Kh_sh[HW4n * CQn];   // 16 KB
    __shared__ __align__(16) short Kl_sh[HW4n * CQn];   // 16 KB
    __shared__ __align__(16) short Vt_sh[2][32 * 136];  // 2 x 8.5 KB (128-key chunks)
    __shared__ __align__(16) short Psh[2][4 * 16 * 40]; // 2 x 5 KB (per-wave P tiles)
    __shared__ __align__(16) float qw_sh[512];
    __shared__ float qbeta_sh[8];
    __shared__ float pbeta_sh[64];

    const int tid  = threadIdx.x;
    const int lane = tid & 63;
    const int w    = tid >> 6;           // wave 0..3
    const int quad = lane >> 4;          // 0..3
    const int c    = lane & 15;          // col lane
    const int b    = blockIdx.x >> 6;    // 64 tiles per batch
    const int tile = blockIdx.x & 63;
    const float gm = gamma[0];

    // ---- stage folded Q weights + biases ----
    for (int idx = tid; idx < 512; idx += 256) {
        int cc = idx & 7, ch = idx >> 3;
        float inv = qs[cc] * rsqrtf(qv[cc] + EPS_BN);
        qw_sh[ch * 8 + cc] = wq[cc * 64 + ch] * inv;
    }
    if (tid < 8) {
        float inv = qs[tid] * rsqrtf(qv[tid] + EPS_BN);
        qbeta_sh[tid] = (bq[tid] - qm[tid]) * inv + qb[tid];
    }
    if (tid < 64) {
        float inv = ps[tid] * rsqrtf(pv[tid] + EPS_BN);
        pbeta_sh[tid] = gm * ((bp[tid] - pm[tid]) * inv + pb[tid]);
    }
    // ---- stage K hi/lo + V^T chunk 0 ----
    const short* Vsrc = g_Vt + (size_t)b * (CVn * HW4n);
    {
        const int4* Kh4 = (const int4*)(g_Kh + (size_t)b * (HW4n * CQn));
        const int4* Kl4 = (const int4*)(g_Kl + (size_t)b * (HW4n * CQn));
        int4* dh = (int4*)Kh_sh;
        int4* dl = (int4*)Kl_sh;
        #pragma unroll
        for (int i = 0; i < 4; ++i) {
            dh[tid + i * 256] = Kh4[tid + i * 256];
            dl[tid + i * 256] = Kl4[tid + i * 256];
        }
        #pragma unroll
        for (int i = 0; i < 2; ++i) {
            int idx4 = tid + (i << 8);            // 512 int4 per chunk
            int ch = idx4 >> 4, k8 = idx4 & 15;
            *(int4*)&Vt_sh[0][ch * 136 + (k8 << 3)] = *(const int4*)(Vsrc + ch * HW4n + (k8 << 3));
        }
    }
    __syncthreads();

    // ---- Q projection: lane computes q for query (tile*64 + w*16 + c) ----
    float q0 = 0.f, q1 = 0.f, q2 = 0.f, q3 = 0.f, q4 = 0.f, q5 = 0.f, q6 = 0.f, q7 = 0.f;
    {
        const float* mp = mem + (size_t)b * (CHn * HWn) + (tile << 6) + (w << 4) + c;
        #pragma unroll
        for (int cc = 0; cc < 16; ++cc) {
            const int ch = (quad << 4) | cc;
            const float mv = mp[ch * HWn];
            const float4 w0 = *(const float4*)&qw_sh[ch * 8];
            const float4 w1 = *(const float4*)&qw_sh[ch * 8 + 4];
            q0 = fmaf(w0.x, mv, q0); q1 = fmaf(w0.y, mv, q1);
            q2 = fmaf(w0.z, mv, q2); q3 = fmaf(w0.w, mv, q3);
            q4 = fmaf(w1.x, mv, q4); q5 = fmaf(w1.y, mv, q5);
            q6 = fmaf(w1.z, mv, q6); q7 = fmaf(w1.w, mv, q7);
        }
        q0 += __shfl_xor(q0, 16); q0 += __shfl_xor(q0, 32); q0 += qbeta_sh[0];
        q1 += __shfl_xor(q1, 16); q1 += __shfl_xor(q1, 32); q1 += qbeta_sh[1];
        q2 += __shfl_xor(q2, 16); q2 += __shfl_xor(q2, 32); q2 += qbeta_sh[2];
        q3 += __shfl_xor(q3, 16); q3 += __shfl_xor(q3, 32); q3 += qbeta_sh[3];
        q4 += __shfl_xor(q4, 16); q4 += __shfl_xor(q4, 32); q4 += qbeta_sh[4];
        q5 += __shfl_xor(q5, 16); q5 += __shfl_xor(q5, 32); q5 += qbeta_sh[5];
        q6 += __shfl_xor(q6, 16); q6 += __shfl_xor(q6, 32); q6 += qbeta_sh[6];
        q7 += __shfl_xor(q7, 16); q7 += __shfl_xor(q7, 32); q7 += qbeta_sh[7];
    }
    // B-frag: quads 0,2 carry Q_hi; quads 1,3 carry Q_lo (K=32 block scheme).
    bf16x8 bqsel;
    {
        unsigned short h0 = f2bf(q0), h1 = f2bf(q1), h2 = f2bf(q2), h3 = f2bf(q3);
        unsigned short h4 = f2bf(q4), h5 = f2bf(q5), h6 = f2bf(q6), h7 = f2bf(q7);
        unsigned short l0 = f2bf(q0 - bf2f(h0)), l1 = f2bf(q1 - bf2f(h1));
        unsigned short l2 = f2bf(q2 - bf2f(h2)), l3 = f2bf(q3 - bf2f(h3));
        unsigned short l4 = f2bf(q4 - bf2f(h4)), l5 = f2bf(q5 - bf2f(h5));
        unsigned short l6 = f2bf(q6 - bf2f(h6)), l7 = f2bf(q7 - bf2f(h7));
        FragI fh, fl;
        fh.i = make_int4((int)(h0 | ((unsigned)h1 << 16)), (int)(h2 | ((unsigned)h3 << 16)),
                         (int)(h4 | ((unsigned)h5 << 16)), (int)(h6 | ((unsigned)h7 << 16)));
        fl.i = make_int4((int)(l0 | ((unsigned)l1 << 16)), (int)(l2 | ((unsigned)l3 << 16)),
                         (int)(l4 | ((unsigned)l5 << 16)), (int)(l6 | ((unsigned)l7 << 16)));
        bqsel = (quad & 1) ? fl.v : fh.v;
    }
    // A-side row source: quads 0,1 read K_hi rows; quads 2,3 read K_lo rows.
    const short* Krow = (quad < 2) ? Kh_sh : Kl_sh;

    // ---- online-softmax state ----
    f32x4 acc0 = {0.f, 0.f, 0.f, 0.f};   // rows=queries 4q+reg, cols=ch c
    f32x4 acc1 = {0.f, 0.f, 0.f, 0.f};   // cols=ch 16+c
    float m_ = -3.0e38f, l_ = 0.f;

    const int pbase = w * 640 + c * 40;
    const int pread = w * 640 + c * 40 + (quad << 3);

    for (int chunk = 0; chunk < 8; ++chunk) {
        const int cur = chunk & 1;
        // ---- prefetch next V chunk into the alternate buffer ----
        if (chunk < 7) {
            const short* Vn = Vsrc + ((chunk + 1) << 7);
            #pragma unroll
            for (int i = 0; i < 2; ++i) {
                int idx4 = tid + (i << 8);
                int ch = idx4 >> 4, k8 = idx4 & 15;
                *(int4*)&Vt_sh[cur ^ 1][ch * 136 + (k8 << 3)] = *(const int4*)(Vn + ch * HW4n + (k8 << 3));
            }
        }
        #pragma unroll
        for (int st = 0; st < 4; ++st) {
            const int kb   = (chunk << 7) + (st << 5);   // global key base
            const int kloc = st << 5;                     // chunk-local base
            const int pbuf = st & 1;                      // P parity (4 steps/chunk, even)

            // ---- QK scores (S^T): one mfma per 16-key half ----
            f32x4 sa = {0.f, 0.f, 0.f, 0.f};
            f32x4 sb = {0.f, 0.f, 0.f, 0.f};
            {
                const bf16x8 a0 = *(const bf16x8*)&Krow[(kb + c) * 8];
                sa = __builtin_amdgcn_mfma_f32_16x16x32_bf16(a0, bqsel, sa, 0, 0, 0);
                const bf16x8 a1 = *(const bf16x8*)&Krow[(kb + 16 + c) * 8];
                sb = __builtin_amdgcn_mfma_f32_16x16x32_bf16(a1, bqsel, sb, 0, 0, 0);
            }

            // ---- online softmax (rows=keys; col c = query) ----
            float mx = fmaxf(fmaxf(fmaxf(sa[0], sa[1]), fmaxf(sa[2], sa[3])),
                             fmaxf(fmaxf(sb[0], sb[1]), fmaxf(sb[2], sb[3])));
            mx = fmaxf(mx, m_);
            mx = fmaxf(mx, __shfl_xor(mx, 16));
            mx = fmaxf(mx, __shfl_xor(mx, 32));
            const float alpha = __expf(m_ - mx);
            m_ = mx;
            const float pa0 = __expf(sa[0] - mx), pa1 = __expf(sa[1] - mx);
            const float pa2 = __expf(sa[2] - mx), pa3 = __expf(sa[3] - mx);
            const float pb0 = __expf(sb[0] - mx), pb1 = __expf(sb[1] - mx);
            const float pb2 = __expf(sb[2] - mx), pb3 = __expf(sb[3] - mx);
            l_ = l_ * alpha + (pa0 + pa1 + pa2 + pa3 + pb0 + pb1 + pb2 + pb3);

            // ---- write P (bf16 pairs) into this wave's double-buffered tile ----
            *(int*)&Psh[pbuf][pbase + (quad << 2)]          = (int)(f2bf(pa0) | ((unsigned)f2bf(pa1) << 16));
            *(int*)&Psh[pbuf][pbase + (quad << 2) + 2]      = (int)(f2bf(pa2) | ((unsigned)f2bf(pa3) << 16));
            *(int*)&Psh[pbuf][pbase + 16 + (quad << 2)]     = (int)(f2bf(pb0) | ((unsigned)f2bf(pb1) << 16));
            *(int*)&Psh[pbuf][pbase + 16 + (quad << 2) + 2] = (int)(f2bf(pb2) | ((unsigned)f2bf(pb3) << 16));

            // ---- rescale acc by alpha of its row-queries (4q+r) ----
            const float a0 = __shfl(alpha, 20 * quad + 0);
            const float a1 = __shfl(alpha, 20 * quad + 1);
            const float a2 = __shfl(alpha, 20 * quad + 2);
            const float a3 = __shfl(alpha, 20 * quad + 3);
            acc0[0] *= a0; acc0[1] *= a1; acc0[2] *= a2; acc0[3] *= a3;
            acc1[0] *= a0; acc1[1] *= a1; acc1[2] *= a2; acc1[3] *= a3;

            // ---- PV: A = P[query][key0..31], B = V^T[key][ch] ----
            const bf16x8 pfrag = *(const bf16x8*)&Psh[pbuf][pread];
            const bf16x8 v0 = *(const bf16x8*)&Vt_sh[cur][c * 136 + kloc + (quad << 3)];
            const bf16x8 v1 = *(const bf16x8*)&Vt_sh[cur][(16 + c) * 136 + kloc + (quad << 3)];
            acc0 = __builtin_amdgcn_mfma_f32_16x16x32_bf16(pfrag, v0, acc0, 0, 0, 0);
            acc1 = __builtin_amdgcn_mfma_f32_16x16x32_bf16(pfrag, v1, acc1, 0, 0, 0);
        }
        __syncthreads();   // next chunk's buffer fully staged; cur free for reuse
    }

    // ---- stage folded out-proj weights (overlay on Vt region) ----
    float* wpf = (float*)Vt_sh;            // [o][36-pitch], 9 KB < 17 KB
    for (int idx = tid; idx < 2048; idx += 256) {
        int o = idx >> 5, cc = idx & 31;
        float inv = ps[o] * rsqrtf(pv[o] + EPS_BN);
        wpf[o * 36 + cc] = wp[o * 32 + cc] * inv * gm;
    }

    // ---- finalize l, normalize, write g (overlay on Kh) ----
    {
        l_ += __shfl_xor(l_, 16);
        l_ += __shfl_xor(l_, 32);
        const float rl = 1.0f / l_;
        const float r0 = __shfl(rl, 20 * quad + 0);
        const float r1 = __shfl(rl, 20 * quad + 1);
        const float r2 = __shfl(rl, 20 * quad + 2);
        const float r3 = __shfl(rl, 20 * quad + 3);
        float* Gsh = (float*)Kh_sh;        // [64 q][36-pitch]
        const int row = (w << 4) + (quad << 2);
        Gsh[(row + 0) * 36 + c] = acc0[0] * r0;
        Gsh[(row + 1) * 36 + c] = acc0[1] * r1;
        Gsh[(row + 2) * 36 + c] = acc0[2] * r2;
        Gsh[(row + 3) * 36 + c] = acc0[3] * r3;
        Gsh[(row + 0) * 36 + 16 + c] = acc1[0] * r0;
        Gsh[(row + 1) * 36 + 16 + c] = acc1[1] * r1;
        Gsh[(row + 2) * 36 + 16 + c] = acc1[2] * r2;
        Gsh[(row + 3) * 36 + 16 + c] = acc1[3] * r3;
    }
    __syncthreads();

    // ---- epilogue: thread (q=tid>>2, r=tid&3) handles o ≡ r (mod 4) ----
    {
        const float* Gsh = (const float*)Kh_sh;
        const int q = tid >> 2, r = tid & 3;
        const float4* gq4 = (const float4*)&Gsh[q * 36];
        float g[32];
        #pragma unroll
        for (int i = 0; i < 8; ++i) {
            const float4 gv = gq4[i];
            g[4*i+0] = gv.x; g[4*i+1] = gv.y; g[4*i+2] = gv.z; g[4*i+3] = gv.w;
        }
        const int n = (tile << 6) + q;
        const float* xp = x + (size_t)b * (CHn * HWn) + n;
        float* op = out + (size_t)b * (CHn * HWn) + n;

        #pragma unroll
        for (int oo = 0; oo < 16; ++oo) {
            const int o = (oo << 2) | r;
            const float4* wr = (const float4*)&wpf[o * 36];
            float po = pbeta_sh[o];
            #pragma unroll
            for (int c4 = 0; c4 < 8; ++c4) {
                const float4 ww = wr[c4];
                po += ww.x * g[4*c4] + ww.y * g[4*c4+1] + ww.z * g[4*c4+2] + ww.w * g[4*c4+3];
            }
            op[o * HWn] = xp[o * HWn] + po;
        }
    }
}

// ------------------------------- launcher ------------------------------------
extern "C" void kernel_launch(void* const* d_in, const int* in_sizes, int n_in,
                              void* d_out, int out_size, void* d_ws, size_t ws_size,
                              hipStream_t stream)
{
    const float* x    = (const float*)d_in[0];
    const float* mem  = (const float*)d_in[1];
    const float* wq   = (const float*)d_in[2];
    const float* bq   = (const float*)d_in[3];
    const float* bnqs = (const float*)d_in[4];
    const float* bnqb = (const float*)d_in[5];
    const float* bnqm = (const float*)d_in[6];
    const float* bnqv = (const float*)d_in[7];
    const float* wk   = (const float*)d_in[8];
    const float* bk   = (const float*)d_in[9];
    const float* bnks = (const float*)d_in[10];
    const float* bnkb = (const float*)d_in[11];
    const float* bnkm = (const float*)d_in[12];
    const float* bnkv = (const float*)d_in[13];
    const float* wv   = (const float*)d_in[14];
    const float* bv   = (const float*)d_in[15];
    const float* bnvs = (const float*)d_in[16];
    const float* bnvb = (const float*)d_in[17];
    const float* bnvm = (const float*)d_in[18];
    const float* bnvv = (const float*)d_in[19];
    const float* wp   = (const float*)d_in[20];
    const float* bp   = (const float*)d_in[21];
    const float* bnps = (const float*)d_in[22];
    const float* bnpb = (const float*)d_in[23];
    const float* bnpm = (const float*)d_in[24];
    const float* bnpv = (const float*)d_in[25];
    const float* gam  = (const float*)d_in[26];

    (void)d_ws; (void)ws_size; (void)in_sizes; (void)n_in; (void)out_size;

    k_proj_kv<<<dim3(256), dim3(192), 0, stream>>>(mem,
        wk, bk, bnks, bnkb, bnkm, bnkv,
        wv, bv, bnvs, bnvb, bnvm, bnvv);
    k_attn7<<<dim3(512), dim3(256), 0, stream>>>(mem, x,
        wq, bq, bnqs, bnqb, bnqm, bnqv,
        wp, bp, bnps, bnpb, bnpm, bnpv, gam,
        (float*)d_out);
}

// Round 11
// 152.456 us; speedup vs baseline: 1.5942x; 1.0127x over previous
//
#include <hip/hip_runtime.h>

#define EPS_BN 1e-5f

// Problem constants: B=8, CH=64, H=W=64  (all I/O float32)
constexpr int Bn   = 8;
constexpr int CHn  = 64;
constexpr int HWn  = 4096;   // 64*64
constexpr int HW4n = 1024;   // pooled keys
constexpr int CQn  = 8;      // CH/8
constexpr int CVn  = 32;     // CH/2

typedef short bf16x8 __attribute__((ext_vector_type(8)));
typedef float f32x4  __attribute__((ext_vector_type(4)));

union FragI { int4 i; bf16x8 v; };

__device__ __forceinline__ unsigned short f2bf(float f) {
    unsigned u = __float_as_uint(f);
    unsigned r = u + 0x7FFFu + ((u >> 16) & 1u);
    return (unsigned short)(r >> 16);
}
__device__ __forceinline__ float bf2f(unsigned short h) {
    return __uint_as_float(((unsigned)h) << 16);
}

// Module-scope scratch; fully rewritten every call.
__device__ __align__(16) short g_Kh[Bn * HW4n * CQn];   // K hi bf16 [b][m][8]
__device__ __align__(16) short g_Kl[Bn * HW4n * CQn];   // K lo bf16 [b][m][8]
__device__ __align__(16) short g_Vt[Bn * CVn * HW4n];   // V^T bf16 [b][ch][key]

// ------------- Kernel A: K,V projection + BN + 2x2 maxpool -------------------
// 256 blocks x 192 threads. Block = one pooled row (32 pooled px) of one batch.
__global__ __launch_bounds__(192)
void k_proj_kv(const float* __restrict__ mem,
               const float* __restrict__ wk,  const float* __restrict__ bk,
               const float* __restrict__ ks,  const float* __restrict__ kb,
               const float* __restrict__ km,  const float* __restrict__ kv,
               const float* __restrict__ wv,  const float* __restrict__ bv_,
               const float* __restrict__ vs,  const float* __restrict__ vb,
               const float* __restrict__ vm,  const float* __restrict__ vv)
{
    __shared__ float wall[2560];   // [ch][40]: c 0..7 = K, 8..39 = V (BN folded)
    __shared__ float beta[40];
    __shared__ float Msh[8192];    // [ch][32 quads][4 px], 32 KB

    const int tid = threadIdx.x;
    for (int idx = tid; idx < 2560; idx += 192) {
        int c = idx % 40, ch = idx / 40;
        float w, inv;
        if (c < 8) { inv = ks[c] * rsqrtf(kv[c] + EPS_BN); w = wk[c * 64 + ch]; }
        else { int c2 = c - 8; inv = vs[c2] * rsqrtf(vv[c2] + EPS_BN); w = wv[c2 * 64 + ch]; }
        wall[ch * 40 + c] = w * inv;
    }
    if (tid < 40) {
        int c = tid;
        if (c < 8) {
            float inv = ks[c] * rsqrtf(kv[c] + EPS_BN);
            beta[c] = (bk[c] - km[c]) * inv + kb[c];
        } else {
            int c2 = c - 8;
            float inv = vs[c2] * rsqrtf(vv[c2] + EPS_BN);
            beta[c] = (bv_[c2] - vm[c2]) * inv + vb[c2];
        }
    }

    const int b = blockIdx.x >> 5;        // 32 blocks per batch
    const int R = blockIdx.x & 31;        // pooled row

    {
        const float* src = mem + (size_t)b * (CHn * HWn) + (R << 7);
        for (int idx = tid; idx < 4096; idx += 192) {
            int ch = idx >> 6, p2 = idx & 63;
            float2 v = *(const float2*)(src + ch * HWn + (p2 << 1));
            int r = p2 >> 5, w2 = p2 & 31;
            *(float2*)&Msh[ch * 128 + (w2 << 2) + (r << 1)] = v;
        }
    }
    __syncthreads();

    if (tid < 160) {
        const int g  = tid % 5;        // 0 = K(8ch), 1..4 = V 8ch each
        const int qd = tid / 5;        // pooled col 0..31
        float acc[4][8];
        #pragma unroll
        for (int p = 0; p < 4; ++p)
            #pragma unroll
            for (int c = 0; c < 8; ++c) acc[p][c] = 0.f;

        for (int ch = 0; ch < 64; ++ch) {
            const float4 mq = *(const float4*)&Msh[ch * 128 + (qd << 2)];
            const float4* wr = (const float4*)&wall[ch * 40 + (g << 3)];
            const float4 w0 = wr[0], w1 = wr[1];
            #pragma unroll
            for (int p = 0; p < 4; ++p) {
                const float mv = (p == 0) ? mq.x : (p == 1) ? mq.y : (p == 2) ? mq.z : mq.w;
                acc[p][0] = fmaf(w0.x, mv, acc[p][0]); acc[p][1] = fmaf(w0.y, mv, acc[p][1]);
                acc[p][2] = fmaf(w0.z, mv, acc[p][2]); acc[p][3] = fmaf(w0.w, mv, acc[p][3]);
                acc[p][4] = fmaf(w1.x, mv, acc[p][4]); acc[p][5] = fmaf(w1.y, mv, acc[p][5]);
                acc[p][6] = fmaf(w1.z, mv, acc[p][6]); acc[p][7] = fmaf(w1.w, mv, acc[p][7]);
            }
        }
        float o[8];
        #pragma unroll
        for (int c = 0; c < 8; ++c)
            o[c] = fmaxf(fmaxf(acc[0][c], acc[1][c]), fmaxf(acc[2][c], acc[3][c]))
                 + beta[(g << 3) + c];

        const int m = (R << 5) + qd;
        if (g == 0) {
            unsigned short hb[8], lb[8];
            #pragma unroll
            for (int c = 0; c < 8; ++c) {
                hb[c] = f2bf(o[c]);
                lb[c] = f2bf(o[c] - bf2f(hb[c]));
            }
            int4 hi4 = make_int4((int)(hb[0] | ((unsigned)hb[1] << 16)),
                                 (int)(hb[2] | ((unsigned)hb[3] << 16)),
                                 (int)(hb[4] | ((unsigned)hb[5] << 16)),
                                 (int)(hb[6] | ((unsigned)hb[7] << 16)));
            int4 lo4 = make_int4((int)(lb[0] | ((unsigned)lb[1] << 16)),
                                 (int)(lb[2] | ((unsigned)lb[3] << 16)),
                                 (int)(lb[4] | ((unsigned)lb[5] << 16)),
                                 (int)(lb[6] | ((unsigned)lb[7] << 16)));
            *(int4*)&g_Kh[((size_t)b * HW4n + m) * CQn] = hi4;
            *(int4*)&g_Kl[((size_t)b * HW4n + m) * CQn] = lo4;
        } else {
            const int ch0 = (g - 1) << 3;
            #pragma unroll
            for (int c = 0; c < 8; ++c)
                g_Vt[(size_t)b * (CVn * HW4n) + (ch0 + c) * HW4n + m] = (short)f2bf(o[c]);
        }
    }
}

// ------ Kernel B: MFMA flash attention, TWO-PASS softmax, barrier-free loop --
// 512 blocks x 256 threads (4 waves). Wave = 16 queries, S^T orientation.
// QK: A = [Khi(q0,q1) | Klo(q2,q3)] rows, B = [Qhi,Qlo,Qhi,Qlo] -> one mfma
// computes the full hi/lo product per 16-key tile.
// Pass 1: scores -> per-lane max (independent steps, 2 shuffles at end).
// Pass 2: p = exp(s - M) with fixed exact M; no rescale, no per-step shuffles;
// V^T read directly from global (L1/L2-hot); P round-trip via per-wave LDS.
__global__ __launch_bounds__(256, 2) __attribute__((amdgpu_waves_per_eu(2, 2)))
void k_attn8(const float* __restrict__ mem,
             const float* __restrict__ x,
             const float* __restrict__ wq, const float* __restrict__ bq,
             const float* __restrict__ qs, const float* __restrict__ qb,
             const float* __restrict__ qm, const float* __restrict__ qv,
             const float* __restrict__ wp, const float* __restrict__ bp,
             const float* __restrict__ ps, const float* __restrict__ pb,
             const float* __restrict__ pm, const float* __restrict__ pv,
             const float* __restrict__ gamma,
             float* __restrict__ out)
{
    __shared__ __align__(16) short Kh_sh[HW4n * CQn];   // 16 KB
    __shared__ __align__(16) short Kl_sh[HW4n * CQn];   // 16 KB (epilogue: wpf overlay)
    __shared__ __align__(16) short Psh[2][4 * 16 * 40]; // 2 x 5 KB (per-wave P tiles)
    __shared__ __align__(16) float qw_sh[512];
    __shared__ float qbeta_sh[8];
    __shared__ float pbeta_sh[64];

    const int tid  = threadIdx.x;
    const int lane = tid & 63;
    const int w    = tid >> 6;           // wave 0..3
    const int quad = lane >> 4;          // 0..3
    const int c    = lane & 15;          // col lane (query within wave-tile)
    const int b    = blockIdx.x >> 6;    // 64 tiles per batch
    const int tile = blockIdx.x & 63;
    const float gm = gamma[0];

    // ---- stage folded Q weights + biases ----
    for (int idx = tid; idx < 512; idx += 256) {
        int cc = idx & 7, ch = idx >> 3;
        float inv = qs[cc] * rsqrtf(qv[cc] + EPS_BN);
        qw_sh[ch * 8 + cc] = wq[cc * 64 + ch] * inv;
    }
    if (tid < 8) {
        float inv = qs[tid] * rsqrtf(qv[tid] + EPS_BN);
        qbeta_sh[tid] = (bq[tid] - qm[tid]) * inv + qb[tid];
    }
    if (tid < 64) {
        float inv = ps[tid] * rsqrtf(pv[tid] + EPS_BN);
        pbeta_sh[tid] = gm * ((bp[tid] - pm[tid]) * inv + pb[tid]);
    }
    // ---- stage K hi/lo ----
    {
        const int4* Kh4 = (const int4*)(g_Kh + (size_t)b * (HW4n * CQn));
        const int4* Kl4 = (const int4*)(g_Kl + (size_t)b * (HW4n * CQn));
        int4* dh = (int4*)Kh_sh;
        int4* dl = (int4*)Kl_sh;
        #pragma unroll
        for (int i = 0; i < 4; ++i) {
            dh[tid + i * 256] = Kh4[tid + i * 256];
            dl[tid + i * 256] = Kl4[tid + i * 256];
        }
    }
    __syncthreads();

    // ---- Q projection: lane computes q for query (tile*64 + w*16 + c) ----
    float q0 = 0.f, q1 = 0.f, q2 = 0.f, q3 = 0.f, q4 = 0.f, q5 = 0.f, q6 = 0.f, q7 = 0.f;
    {
        const float* mp = mem + (size_t)b * (CHn * HWn) + (tile << 6) + (w << 4) + c;
        #pragma unroll
        for (int cc = 0; cc < 16; ++cc) {
            const int ch = (quad << 4) | cc;
            const float mv = mp[ch * HWn];
            const float4 w0 = *(const float4*)&qw_sh[ch * 8];
            const float4 w1 = *(const float4*)&qw_sh[ch * 8 + 4];
            q0 = fmaf(w0.x, mv, q0); q1 = fmaf(w0.y, mv, q1);
            q2 = fmaf(w0.z, mv, q2); q3 = fmaf(w0.w, mv, q3);
            q4 = fmaf(w1.x, mv, q4); q5 = fmaf(w1.y, mv, q5);
            q6 = fmaf(w1.z, mv, q6); q7 = fmaf(w1.w, mv, q7);
        }
        q0 += __shfl_xor(q0, 16); q0 += __shfl_xor(q0, 32); q0 += qbeta_sh[0];
        q1 += __shfl_xor(q1, 16); q1 += __shfl_xor(q1, 32); q1 += qbeta_sh[1];
        q2 += __shfl_xor(q2, 16); q2 += __shfl_xor(q2, 32); q2 += qbeta_sh[2];
        q3 += __shfl_xor(q3, 16); q3 += __shfl_xor(q3, 32); q3 += qbeta_sh[3];
        q4 += __shfl_xor(q4, 16); q4 += __shfl_xor(q4, 32); q4 += qbeta_sh[4];
        q5 += __shfl_xor(q5, 16); q5 += __shfl_xor(q5, 32); q5 += qbeta_sh[5];
        q6 += __shfl_xor(q6, 16); q6 += __shfl_xor(q6, 32); q6 += qbeta_sh[6];
        q7 += __shfl_xor(q7, 16); q7 += __shfl_xor(q7, 32); q7 += qbeta_sh[7];
    }
    // B-frag: quads 0,2 carry Q_hi; quads 1,3 carry Q_lo (K=32 block scheme).
    bf16x8 bqsel;
    {
        unsigned short h0 = f2bf(q0), h1 = f2bf(q1), h2 = f2bf(q2), h3 = f2bf(q3);
        unsigned short h4 = f2bf(q4), h5 = f2bf(q5), h6 = f2bf(q6), h7 = f2bf(q7);
        unsigned short l0 = f2bf(q0 - bf2f(h0)), l1 = f2bf(q1 - bf2f(h1));
        unsigned short l2 = f2bf(q2 - bf2f(h2)), l3 = f2bf(q3 - bf2f(h3));
        unsigned short l4 = f2bf(q4 - bf2f(h4)), l5 = f2bf(q5 - bf2f(h5));
        unsigned short l6 = f2bf(q6 - bf2f(h6)), l7 = f2bf(q7 - bf2f(h7));
        FragI fh, fl;
        fh.i = make_int4((int)(h0 | ((unsigned)h1 << 16)), (int)(h2 | ((unsigned)h3 << 16)),
                         (int)(h4 | ((unsigned)h5 << 16)), (int)(h6 | ((unsigned)h7 << 16)));
        fl.i = make_int4((int)(l0 | ((unsigned)l1 << 16)), (int)(l2 | ((unsigned)l3 << 16)),
                         (int)(l4 | ((unsigned)l5 << 16)), (int)(l6 | ((unsigned)l7 << 16)));
        bqsel = (quad & 1) ? fl.v : fh.v;
    }
    // A-side row source: quads 0,1 read K_hi rows; quads 2,3 read K_lo rows.
    const short* Krow = (quad < 2) ? Kh_sh : Kl_sh;

    // ================= PASS 1: global max (independent steps) ================
    float Mloc = -3.0e38f;
    #pragma unroll 4
    for (int st = 0; st < 32; ++st) {
        const int kb = st << 5;
        f32x4 sa = {0.f, 0.f, 0.f, 0.f};
        f32x4 sb = {0.f, 0.f, 0.f, 0.f};
        const bf16x8 a0 = *(const bf16x8*)&Krow[(kb + c) * 8];
        sa = __builtin_amdgcn_mfma_f32_16x16x32_bf16(a0, bqsel, sa, 0, 0, 0);
        const bf16x8 a1 = *(const bf16x8*)&Krow[(kb + 16 + c) * 8];
        sb = __builtin_amdgcn_mfma_f32_16x16x32_bf16(a1, bqsel, sb, 0, 0, 0);
        const float ma = fmaxf(fmaxf(sa[0], sa[1]), fmaxf(sa[2], sa[3]));
        const float mb = fmaxf(fmaxf(sb[0], sb[1]), fmaxf(sb[2], sb[3]));
        Mloc = fmaxf(Mloc, fmaxf(ma, mb));
    }
    Mloc = fmaxf(Mloc, __shfl_xor(Mloc, 16));
    Mloc = fmaxf(Mloc, __shfl_xor(Mloc, 32));
    const float M = Mloc;   // exact column max (same score computation)

    // ================= PASS 2: exp + PV (no rescale, no shuffles) ============
    float l_ = 0.f;
    f32x4 acc0 = {0.f, 0.f, 0.f, 0.f};   // rows=queries, cols=ch c
    f32x4 acc1 = {0.f, 0.f, 0.f, 0.f};   // cols=ch 16+c
    const short* Vrow0 = g_Vt + (size_t)b * (CVn * HW4n) + c * HW4n + (quad << 3);
    const short* Vrow1 = Vrow0 + 16 * HW4n;
    const int pbase = w * 640 + c * 40;
    const int pread = w * 640 + c * 40 + (quad << 3);

    #pragma unroll 2
    for (int st = 0; st < 32; ++st) {
        const int kb = st << 5;
        // V prefetch (global, L1/L2-hot; consumed ~40 instrs later)
        const bf16x8 v0 = *(const bf16x8*)(Vrow0 + kb);
        const bf16x8 v1 = *(const bf16x8*)(Vrow1 + kb);
        // QK scores
        f32x4 sa = {0.f, 0.f, 0.f, 0.f};
        f32x4 sb = {0.f, 0.f, 0.f, 0.f};
        const bf16x8 a0 = *(const bf16x8*)&Krow[(kb + c) * 8];
        sa = __builtin_amdgcn_mfma_f32_16x16x32_bf16(a0, bqsel, sa, 0, 0, 0);
        const bf16x8 a1 = *(const bf16x8*)&Krow[(kb + 16 + c) * 8];
        sb = __builtin_amdgcn_mfma_f32_16x16x32_bf16(a1, bqsel, sb, 0, 0, 0);
        // exp with fixed M
        const float pa0 = __expf(sa[0] - M), pa1 = __expf(sa[1] - M);
        const float pa2 = __expf(sa[2] - M), pa3 = __expf(sa[3] - M);
        const float pb0 = __expf(sb[0] - M), pb1 = __expf(sb[1] - M);
        const float pb2 = __expf(sb[2] - M), pb3 = __expf(sb[3] - M);
        l_ += ((pa0 + pa1) + (pa2 + pa3)) + ((pb0 + pb1) + (pb2 + pb3));
        // P round-trip through per-wave LDS tile (same-wave, program-ordered)
        const int pbuf = st & 1;
        *(int*)&Psh[pbuf][pbase + (quad << 2)]          = (int)(f2bf(pa0) | ((unsigned)f2bf(pa1) << 16));
        *(int*)&Psh[pbuf][pbase + (quad << 2) + 2]      = (int)(f2bf(pa2) | ((unsigned)f2bf(pa3) << 16));
        *(int*)&Psh[pbuf][pbase + 16 + (quad << 2)]     = (int)(f2bf(pb0) | ((unsigned)f2bf(pb1) << 16));
        *(int*)&Psh[pbuf][pbase + 16 + (quad << 2) + 2] = (int)(f2bf(pb2) | ((unsigned)f2bf(pb3) << 16));
        const bf16x8 pfrag = *(const bf16x8*)&Psh[pbuf][pread];
        // PV
        acc0 = __builtin_amdgcn_mfma_f32_16x16x32_bf16(pfrag, v0, acc0, 0, 0, 0);
        acc1 = __builtin_amdgcn_mfma_f32_16x16x32_bf16(pfrag, v1, acc1, 0, 0, 0);
    }

    __syncthreads();   // all waves done reading Kh/Kl

    // ---- stage folded out-proj weights (overlay on Kl) ----
    float* wpf = (float*)Kl_sh;            // [o][36-pitch], 9.2 KB < 16 KB
    for (int idx = tid; idx < 2048; idx += 256) {
        int o = idx >> 5, cc = idx & 31;
        float inv = ps[o] * rsqrtf(pv[o] + EPS_BN);
        wpf[o * 36 + cc] = wp[o * 32 + cc] * inv * gm;
    }

    // ---- finalize l, normalize, write g (overlay on Kh) ----
    {
        l_ += __shfl_xor(l_, 16);
        l_ += __shfl_xor(l_, 32);
        const float rl = 1.0f / l_;
        const float r0 = __shfl(rl, 20 * quad + 0);
        const float r1 = __shfl(rl, 20 * quad + 1);
        const float r2 = __shfl(rl, 20 * quad + 2);
        const float r3 = __shfl(rl, 20 * quad + 3);
        float* Gsh = (float*)Kh_sh;        // [64 q][36-pitch]
        const int row = (w << 4) + (quad << 2);
        Gsh[(row + 0) * 36 + c] = acc0[0] * r0;
        Gsh[(row + 1) * 36 + c] = acc0[1] * r1;
        Gsh[(row + 2) * 36 + c] = acc0[2] * r2;
        Gsh[(row + 3) * 36 + c] = acc0[3] * r3;
        Gsh[(row + 0) * 36 + 16 + c] = acc1[0] * r0;
        Gsh[(row + 1) * 36 + 16 + c] = acc1[1] * r1;
        Gsh[(row + 2) * 36 + 16 + c] = acc1[2] * r2;
        Gsh[(row + 3) * 36 + 16 + c] = acc1[3] * r3;
    }
    __syncthreads();

    // ---- epilogue: thread (q=tid>>2, r=tid&3) handles o ≡ r (mod 4) ----
    {
        const float* Gsh = (const float*)Kh_sh;
        const int q = tid >> 2, r = tid & 3;
        const float4* gq4 = (const float4*)&Gsh[q * 36];
        float g[32];
        #pragma unroll
        for (int i = 0; i < 8; ++i) {
            const float4 gv = gq4[i];
            g[4*i+0] = gv.x; g[4*i+1] = gv.y; g[4*i+2] = gv.z; g[4*i+3] = gv.w;
        }
        const int n = (tile << 6) + q;
        const float* xp = x + (size_t)b * (CHn * HWn) + n;
        float* op = out + (size_t)b * (CHn * HWn) + n;

        #pragma unroll
        for (int oo = 0; oo < 16; ++oo) {
            const int o = (oo << 2) | r;
            const float4* wr = (const float4*)&wpf[o * 36];
            float po = pbeta_sh[o];
            #pragma unroll
            for (int c4 = 0; c4 < 8; ++c4) {
                const float4 ww = wr[c4];
                po += ww.x * g[4*c4] + ww.y * g[4*c4+1] + ww.z * g[4*c4+2] + ww.w * g[4*c4+3];
            }
            op[o * HWn] = xp[o * HWn] + po;
        }
    }
}

// ------------------------------- launcher ------------------------------------
extern "C" void kernel_launch(void* const* d_in, const int* in_sizes, int n_in,
                              void* d_out, int out_size, void* d_ws, size_t ws_size,
                              hipStream_t stream)
{
    const float* x    = (const float*)d_in[0];
    const float* mem  = (const float*)d_in[1];
    const float* wq   = (const float*)d_in[2];
    const float* bq   = (const float*)d_in[3];
    const float* bnqs = (const float*)d_in[4];
    const float* bnqb = (const float*)d_in[5];
    const float* bnqm = (const float*)d_in[6];
    const float* bnqv = (const float*)d_in[7];
    const float* wk   = (const float*)d_in[8];
    const float* bk   = (const float*)d_in[9];
    const float* bnks = (const float*)d_in[10];
    const float* bnkb = (const float*)d_in[11];
    const float* bnkm = (const float*)d_in[12];
    const float* bnkv = (const float*)d_in[13];
    const float* wv   = (const float*)d_in[14];
    const float* bv   = (const float*)d_in[15];
    const float* bnvs = (const float*)d_in[16];
    const float* bnvb = (const float*)d_in[17];
    const float* bnvm = (const float*)d_in[18];
    const float* bnvv = (const float*)d_in[19];
    const float* wp   = (const float*)d_in[20];
    const float* bp   = (const float*)d_in[21];
    const float* bnps = (const float*)d_in[22];
    const float* bnpb = (const float*)d_in[23];
    const float* bnpm = (const float*)d_in[24];
    const float* bnpv = (const float*)d_in[25];
    const float* gam  = (const float*)d_in[26];

    (void)d_ws; (void)ws_size; (void)in_sizes; (void)n_in; (void)out_size;

    k_proj_kv<<<dim3(256), dim3(192), 0, stream>>>(mem,
        wk, bk, bnks, bnkb, bnkm, bnkv,
        wv, bv, bnvs, bnvb, bnvm, bnvv);
    k_attn8<<<dim3(512), dim3(256), 0, stream>>>(mem, x,
        wq, bq, bnqs, bnqb, bnqm, bnqv,
        wp, bp, bnps, bnpb, bnpm, bnpv, gam,
        (float*)d_out);
}